// Round 2
// baseline (1009.191 us; speedup 1.0000x reference)
//
#include <hip/hip_runtime.h>
#include <hip/hip_bf16.h>
#include <math.h>

typedef __hip_bfloat16 bf16;
typedef __attribute__((ext_vector_type(8))) short short8;   // 8 bf16 (4 VGPRs)
typedef __attribute__((ext_vector_type(4))) float f32x4;

constexpr int B_ = 8, S_ = 1024, F_ = 8, D_ = 512, H_ = 8, E_ = 4;
constexpr int T_  = B_ * S_;       // 8192 tokens
constexpr int D3_ = 3 * D_;        // 1536
constexpr int CAP_ = T_ * 2 + E_ * 128;   // sparse row capacity (top-2, 128-pad/expert)

__device__ __forceinline__ float b2f(bf16 v) { return __bfloat162float(v); }
__device__ __forceinline__ float ldin(const void* p, size_t i, int bf) {
  return bf ? __bfloat162float(((const bf16*)p)[i]) : ((const float*)p)[i];
}
__device__ __forceinline__ void gload16(const void* g, void* l) {
  __builtin_amdgcn_global_load_lds((const __attribute__((address_space(1))) unsigned int*)g,
                                   (__attribute__((address_space(3))) unsigned int*)l, 16, 0, 0);
}

// ---------------- dtype detector ----------------
__global__ void detect_kernel(const void* __restrict__ x, int* __restrict__ flag) {
  if (threadIdx.x == 0 && blockIdx.x == 0) {
    const unsigned short* u = (const unsigned short*)x;
    int c = 0;
    for (int i = 0; i < 256; i += 2) {
      int ex = (u[i] >> 7) & 0xFF;
      if (ex >= 96 && ex <= 144) c++;
    }
    flag[0] = (c >= 64) ? 1 : 0;
  }
}

// ---------------- weight pre-convert: fp32 (or bf16 copy) -> bf16 scratch ----------
// Concatenates two source regions [A: nA elems][B: rest]. 8 elems/thread, vectorized.
__global__ __launch_bounds__(256) void convw_kernel(const void* __restrict__ Asrc, size_t offA,
                                                    size_t nA,
                                                    const void* __restrict__ Bsrc, size_t offB,
                                                    bf16* __restrict__ dst,
                                                    const int* __restrict__ flag) {
  const int bf = flag[0];
  size_t i = ((size_t)blockIdx.x * 256 + threadIdx.x) * 8;
  const void* s = Asrc;
  size_t so = offA + i;
  if (i >= nA) { s = Bsrc; so = offB + (i - nA); }
  if (bf) {
    *(short8*)(dst + i) = *(const short8*)((const bf16*)s + so);
  } else {
    const float* sp = (const float*)s + so;
    short8 v;
#pragma unroll
    for (int u = 0; u < 8; u++) { bf16 t = __float2bfloat16(sp[u]); v[u] = *(short*)&t; }
    *(short8*)(dst + i) = v;
  }
}

// ---------------- instance norm over time axis ----------------
__global__ __launch_bounds__(256) void instnorm_kernel(const void* __restrict__ x,
                                                       float* __restrict__ xn,
                                                       const int* __restrict__ flag) {
  const int bf = flag[0];
  int b = blockIdx.x / F_, f = blockIdx.x % F_;
  int tid = threadIdx.x;
  __shared__ float red[256];
  const int base = b * S_ * F_ + f;
  float s = 0.f;
  for (int j = tid; j < S_; j += 256) s += ldin(x, base + j * F_, bf);
  red[tid] = s; __syncthreads();
  for (int w = 128; w; w >>= 1) { if (tid < w) red[tid] += red[tid + w]; __syncthreads(); }
  float mean = red[0] / S_;
  __syncthreads();
  float v = 0.f;
  for (int j = tid; j < S_; j += 256) { float d = ldin(x, base + j * F_, bf) - mean; v += d * d; }
  red[tid] = v; __syncthreads();
  for (int w = 128; w; w >>= 1) { if (tid < w) red[tid] += red[tid + w]; __syncthreads(); }
  float inv = 1.f / (sqrtf(red[0] / (float)(S_ - 1)) + 1e-5f);
  for (int j = tid; j < S_; j += 256) xn[base + j * F_] = (ldin(x, base + j * F_, bf) - mean) * inv;
}

// ---------------- input projection + freq emb + positional encoding ----------------
__global__ __launch_bounds__(256) void input_proj_kernel(const float* __restrict__ xn,
                                                         const void* __restrict__ Wp,
                                                         const void* __restrict__ bp,
                                                         const void* __restrict__ femb,
                                                         const int* __restrict__ freq_idx,
                                                         float* __restrict__ h,
                                                         bf16* __restrict__ hb16,
                                                         const int* __restrict__ flag) {
  const int bf = flag[0];
  int idx = blockIdx.x * 256 + threadIdx.x;
  int d = idx % D_;
  int t = idx / D_;
  int s = t % S_;
  int fi = freq_idx[0];
  float acc = ldin(bp, d, bf) + ldin(femb, (size_t)fi * D_ + d, bf);
  int i2 = d & ~1;
  const float cexp = -9.2103403719761836f / (float)D_;
  float ang = (float)s * expf((float)i2 * cexp);
  acc += (d & 1) ? cosf(ang) : sinf(ang);
  const float* xr = xn + t * F_;
#pragma unroll
  for (int f = 0; f < F_; f++) acc += xr[f] * ldin(Wp, (size_t)d * F_ + f, bf);
  h[idx] = acc;
  hb16[idx] = __float2bfloat16(acc);
}

// ---------------- dense MFMA GEMM, BK=32, dbuf single-barrier K-loop, XCD swizzle ----
// B operand is pre-converted bf16 (async global_load_lds both operands).
// MODE 3: C bf16 = acc + bias  (QKV). MODE 0: partial bf16 slice per z (O-proj).
// Requires gridDim.y % 8 == 0 for the swizzle.
template <int MODE>
__global__ __launch_bounds__(256) void mfma_gemm(
    const bf16* __restrict__ A, const bf16* __restrict__ Wt,
    const void* __restrict__ bias, size_t boff, void* __restrict__ C_,
    int Kd, int lda, int ldb, int ldc, const int* __restrict__ flag) {
  const int wbf = flag[0];
  __shared__ bf16 As[2][128][32];
  __shared__ bf16 Bs[2][128][32];
  const int tid = threadIdx.x;
  const int ln = tid & 63, wv = tid >> 6;
  int id = blockIdx.x + gridDim.x * blockIdx.y;
  int xcd = id & 7, idq = id >> 3;
  const int n0 = (idq % gridDim.x) * 128;
  const int m0 = (xcd + 8 * (idq / gridDim.x)) * 128;
  const int wr = (wv >> 1) * 64, wc = (wv & 1) * 64;
  const int mrow = ln & 15, quad = ln >> 4;
  const int srow = ln >> 2;
  const int skof = (ln & 3) * 8;
  const int kchunk = Kd / gridDim.z;
  const int kbeg = blockIdx.z * kchunk;
  const int kend = kbeg + kchunk;

  auto stage = [&](int pb, int k0) {
#pragma unroll
    for (int j = 0; j < 2; j++) {
      int row = 16 * (4 * j + wv) + srow;
      gload16(A + (size_t)(m0 + row) * lda + k0 + skof,
              (char*)&As[pb][0][0] + (size_t)(4 * j + wv) * 1024);
    }
#pragma unroll
    for (int j = 0; j < 2; j++) {
      int row = 16 * (4 * j + wv) + srow;
      gload16(Wt + (size_t)(n0 + row) * ldb + k0 + skof,
              (char*)&Bs[pb][0][0] + (size_t)(4 * j + wv) * 1024);
    }
  };

  f32x4 acc[4][4];
#pragma unroll
  for (int i = 0; i < 4; i++)
#pragma unroll
    for (int j = 0; j < 4; j++) acc[i][j] = (f32x4){0.f, 0.f, 0.f, 0.f};

  stage(0, kbeg);
  int p = 0;
  for (int k0 = kbeg; k0 < kend; k0 += 32) {
    __syncthreads();                       // drains prefetch into buf p (vmcnt before barrier)
    if (k0 + 32 < kend) stage(p ^ 1, k0 + 32);   // in flight during compute
    short8 af[4], bfr[4];
#pragma unroll
    for (int t = 0; t < 4; t++) {
      af[t]  = *(const short8*)&As[p][wr + t * 16 + mrow][quad * 8];
      bfr[t] = *(const short8*)&Bs[p][wc + t * 16 + mrow][quad * 8];
    }
#pragma unroll
    for (int i = 0; i < 4; i++)
#pragma unroll
      for (int j = 0; j < 4; j++)
        acc[i][j] = __builtin_amdgcn_mfma_f32_16x16x32_bf16(af[i], bfr[j], acc[i][j], 0, 0, 0);
    p ^= 1;
  }

  bf16* slice = (MODE == 0) ? (bf16*)C_ + (size_t)blockIdx.z * T_ * D_ : (bf16*)C_;
#pragma unroll
  for (int tj = 0; tj < 4; tj++) {
    int n = n0 + wc + tj * 16 + mrow;
    float bv = (MODE == 3) ? ldin(bias, boff + n, wbf) : 0.f;
#pragma unroll
    for (int ti = 0; ti < 4; ti++) {
      int mbase = m0 + wr + ti * 16 + quad * 4;
#pragma unroll
      for (int r = 0; r < 4; r++) {
        int m = mbase + r;
        float v = acc[ti][tj][r];
        slice[(size_t)m * ldc + n] = __float2bfloat16(MODE == 3 ? v + bv : v);
      }
    }
  }
}

// ---------------- MFMA flash attention: 128-query tile, swizzled V transpose --------
// LDS: Q-tile buffer aliases the P buffer (Q fragments are register-resident before
// the first P write; two barriers separate the last Q read from the first P write).
// 36.9 KB/block -> 4 blocks/CU (was 54.4 KB -> 2 blocks/CU).
// Block remap: all 8 query-tiles of one (b,h) land on one XCD (id&7 picks XCD) so
// the K/V panel is fetched into exactly one L2.
__global__ __launch_bounds__(256) void attn_kernel(const bf16* __restrict__ qkv,
                                                   bf16* __restrict__ o) {
  __shared__ bf16 QP[128][72];   // Q tile, then P tile (aliased)
  __shared__ bf16 Ks[64][72];
  __shared__ bf16 Vt[64][72];    // [d][k ^ swz(d)]
  const int tid = threadIdx.x;
  const int ln = tid & 63, wv = tid >> 6;
  const int mrow = ln & 15, quad = ln >> 4;
  // XCD-aware remap: xcd = id&7 (HW round-robin); same (b,h) stays on one XCD
  const int id = blockIdx.x;
  const int xcd = id & 7, j = id >> 3;
  const int qt = j & 7;
  const int pr = xcd + 8 * (j >> 3);     // 0..63
  const int hh = pr & 7, b = pr >> 3;
  const int q0 = qt * 128;
  const int sr = tid >> 2;
  const int sg = tid & 3;
  const int sc = sg * 8;

#pragma unroll
  for (int p = 0; p < 2; p++) {
    int row = sr + p * 64;
    const bf16* src = qkv + (size_t)(b * S_ + q0 + row) * D3_ + hh * 64;
    *(short8*)&QP[row][sc]      = *(const short8*)(src + sc);
    *(short8*)&QP[row][sc + 32] = *(const short8*)(src + sc + 32);
  }
  __syncthreads();
  short8 aq[2][2];
#pragma unroll
  for (int g = 0; g < 2; g++) {
    aq[g][0] = *(const short8*)&QP[wv * 32 + g * 16 + mrow][quad * 8];
    aq[g][1] = *(const short8*)&QP[wv * 32 + g * 16 + mrow][quad * 8 + 32];
  }

  float m_st[2][4], l_st[2][4];
  f32x4 oacc[2][4];
#pragma unroll
  for (int g = 0; g < 2; g++)
#pragma unroll
    for (int t = 0; t < 4; t++) {
      m_st[g][t] = -1e30f; l_st[g][t] = 0.f;
      oacc[g][t] = (f32x4){0.f, 0.f, 0.f, 0.f};
    }

  for (int kt = 0; kt < 16; kt++) {
    int k0 = kt * 64;
    __syncthreads();
    {
      const bf16* src = qkv + (size_t)(b * S_ + k0 + sr) * D3_ + D_ + hh * 64;
      *(short8*)&Ks[sr][sc]      = *(const short8*)(src + sc);
      *(short8*)&Ks[sr][sc + 32] = *(const short8*)(src + sc + 32);
    }
    {
      const bf16* src = qkv + (size_t)(b * S_ + k0 + sr) * D3_ + 2 * D_ + hh * 64;
      short8 v0 = *(const short8*)(src + sc);
      short8 v1 = *(const short8*)(src + sc + 32);
      int col0 = sr ^ (sg << 4);
      int col1 = sr ^ (((sg + 4) & 3) << 4);
#pragma unroll
      for (int u = 0; u < 8; u++) {
        *(short*)&Vt[sc + u][col0]      = v0[u];
        *(short*)&Vt[sc + 32 + u][col1] = v1[u];
      }
    }
    __syncthreads();
    f32x4 s[2][4];
#pragma unroll
    for (int g = 0; g < 2; g++)
#pragma unroll
      for (int t = 0; t < 4; t++) {
        s[g][t] = (f32x4){0.f, 0.f, 0.f, 0.f};
#pragma unroll
        for (int ks = 0; ks < 2; ks++) {
          short8 bk = *(const short8*)&Ks[t * 16 + mrow][quad * 8 + ks * 32];
          s[g][t] = __builtin_amdgcn_mfma_f32_16x16x32_bf16(aq[g][ks], bk, s[g][t], 0, 0, 0);
        }
      }
#pragma unroll
    for (int g = 0; g < 2; g++)
#pragma unroll
      for (int r = 0; r < 4; r++) {
        float rm = fmaxf(fmaxf(s[g][0][r], s[g][1][r]), fmaxf(s[g][2][r], s[g][3][r])) * 0.125f;
#pragma unroll
        for (int off = 8; off; off >>= 1) rm = fmaxf(rm, __shfl_xor(rm, off, 64));
        float mnew = fmaxf(m_st[g][r], rm);
        float alpha = __expf(m_st[g][r] - mnew);
        m_st[g][r] = mnew;
        float rs = 0.f;
#pragma unroll
        for (int t = 0; t < 4; t++) {
          float p = __expf(s[g][t][r] * 0.125f - mnew);
          rs += p;
          QP[wv * 32 + g * 16 + quad * 4 + r][t * 16 + mrow] = __float2bfloat16(p);
        }
#pragma unroll
        for (int off = 8; off; off >>= 1) rs += __shfl_xor(rs, off, 64);
        l_st[g][r] = l_st[g][r] * alpha + rs;
#pragma unroll
        for (int t = 0; t < 4; t++) oacc[g][t][r] *= alpha;
      }
#pragma unroll
    for (int g = 0; g < 2; g++) {
      short8 ap[2];
      ap[0] = *(const short8*)&QP[wv * 32 + g * 16 + mrow][quad * 8];
      ap[1] = *(const short8*)&QP[wv * 32 + g * 16 + mrow][quad * 8 + 32];
#pragma unroll
      for (int t = 0; t < 4; t++) {
        int d = t * 16 + mrow;
        int swz = ((d >> 3) & 3) << 4;
#pragma unroll
        for (int ks = 0; ks < 2; ks++) {
          short8 bv = *(const short8*)&Vt[d][(quad * 8 + ks * 32) ^ swz];
          oacc[g][t] = __builtin_amdgcn_mfma_f32_16x16x32_bf16(ap[ks], bv, oacc[g][t], 0, 0, 0);
        }
      }
    }
  }
#pragma unroll
  for (int g = 0; g < 2; g++)
#pragma unroll
    for (int r = 0; r < 4; r++) {
      float inv = 1.f / l_st[g][r];
      size_t base = (size_t)(b * S_ + q0 + wv * 32 + g * 16 + quad * 4 + r) * D_ + hh * 64;
#pragma unroll
      for (int t = 0; t < 4; t++)
        o[base + t * 16 + mrow] = __float2bfloat16(oacc[g][t][r] * inv);
    }
}

// ---------------- fused: sum partial slices + bias + residual + LayerNorm ----------
__global__ __launch_bounds__(256) void reduce_ln_kernel(float* __restrict__ h,
                                                        bf16* __restrict__ hb16,
                                                        const bf16* __restrict__ ps,
                                                        int nsl, int mode,
                                                        const void* __restrict__ bias,
                                                        size_t boff,
                                                        const float* __restrict__ cw,
                                                        const void* __restrict__ eb2p,
                                                        size_t e2off,
                                                        const void* __restrict__ g,
                                                        const void* __restrict__ beta,
                                                        size_t off,
                                                        const int* __restrict__ flag) {
  const int bf = flag[0];
  int t = blockIdx.x, tid = threadIdx.x;
  __shared__ float r1[256], r2[256];
  const size_t base = (size_t)t * D_;
  float o0 = 0.f, o1 = 0.f;
  for (int s = 0; s < nsl; s++) {
    o0 += b2f(ps[(size_t)s * T_ * D_ + base + tid]);
    o1 += b2f(ps[(size_t)s * T_ * D_ + base + tid + 256]);
  }
  if (mode == 0) {
    o0 += ldin(bias, boff + tid, bf);
    o1 += ldin(bias, boff + tid + 256, bf);
  } else {
#pragma unroll
    for (int e = 0; e < 4; e++) {
      float w = cw[t * 4 + e];
      o0 += w * ldin(eb2p, e2off + e * D_ + tid, bf);
      o1 += w * ldin(eb2p, e2off + e * D_ + tid + 256, bf);
    }
  }
  float* hr = h + base;
  float v0 = hr[tid] + o0;
  float v1 = hr[tid + 256] + o1;
  r1[tid] = v0 + v1;
  r2[tid] = v0 * v0 + v1 * v1;
  __syncthreads();
  for (int w = 128; w; w >>= 1) { if (tid < w) { r1[tid] += r1[tid + w]; r2[tid] += r2[tid + w]; } __syncthreads(); }
  float mean = r1[0] * (1.f / D_);
  float var  = r2[0] * (1.f / D_) - mean * mean;
  float rstd = rsqrtf(var + 1e-5f);
  float n0 = (v0 - mean) * rstd * ldin(g, off + tid, bf) + ldin(beta, off + tid, bf);
  float n1 = (v1 - mean) * rstd * ldin(g, off + tid + 256, bf) + ldin(beta, off + tid + 256, bf);
  hr[tid] = n0;
  hr[tid + 256] = n1;
  hb16[base + tid] = __float2bfloat16(n0);
  hb16[base + tid + 256] = __float2bfloat16(n1);
}

// ---------------- MoE gating: softmax over E=4, top-2; emits routing info ----------
__global__ __launch_bounds__(256) void gate_kernel(const float* __restrict__ hbuf,
                                                   const void* __restrict__ gw, size_t gwoff,
                                                   const void* __restrict__ gb, size_t gboff,
                                                   float* __restrict__ cw,
                                                   int* __restrict__ einfo,
                                                   float* __restrict__ w0a,
                                                   float* __restrict__ w1a,
                                                   const int* __restrict__ flag) {
  const int bf = flag[0];
  int lane = threadIdx.x & 63, wv = threadIdx.x >> 6;
  int t = blockIdx.x * 4 + wv;
  const float* xr = hbuf + (size_t)t * D_;
  float a[4] = {0, 0, 0, 0};
  for (int d = lane; d < D_; d += 64) {
    float xv = xr[d];
#pragma unroll
    for (int e = 0; e < 4; e++) a[e] += xv * ldin(gw, gwoff + e * D_ + d, bf);
  }
#pragma unroll
  for (int e = 0; e < 4; e++)
    for (int off = 32; off; off >>= 1) a[e] += __shfl_xor(a[e], off, 64);
  if (lane == 0) {
    float lg[4];
#pragma unroll
    for (int e = 0; e < 4; e++) lg[e] = a[e] + ldin(gb, gboff + e, bf);
    float m = fmaxf(fmaxf(lg[0], lg[1]), fmaxf(lg[2], lg[3]));
    float p[4], s = 0.f;
#pragma unroll
    for (int e = 0; e < 4; e++) { p[e] = __expf(lg[e] - m); s += p[e]; }
#pragma unroll
    for (int e = 0; e < 4; e++) p[e] /= s;
    int i0 = 0;
    for (int e = 1; e < 4; e++) if (p[e] > p[i0]) i0 = e;
    int i1 = -1;
    for (int e = 0; e < 4; e++) if (e != i0 && (i1 < 0 || p[e] > p[i1])) i1 = e;
    float s2 = p[i0] + p[i1];
    float ww0 = p[i0] / s2, ww1 = p[i1] / s2;
    float outw[4] = {0, 0, 0, 0};
    outw[i0] = ww0; outw[i1] = ww1;
#pragma unroll
    for (int e = 0; e < 4; e++) cw[t * 4 + e] = outw[e];
    einfo[t] = i0 | (i1 << 4);
    w0a[t] = ww0; w1a[t] = ww1;
  }
}

// ---------------- route scan: counts -> offsets + tile table (1 block) ----------------
__global__ __launch_bounds__(256) void route_scan_kernel(const int* __restrict__ einfo,
                                                         int* __restrict__ off,
                                                         int* __restrict__ endp,
                                                         int* __restrict__ cur,
                                                         int* __restrict__ tmap) {
  __shared__ int red[4][256];
  int tid = threadIdx.x;
  int c[4] = {0, 0, 0, 0};
  for (int t = tid; t < T_; t += 256) {
    int inf = einfo[t];
    c[inf & 15]++;
    c[(inf >> 4) & 15]++;
  }
#pragma unroll
  for (int e = 0; e < 4; e++) red[e][tid] = c[e];
  __syncthreads();
  for (int w = 128; w; w >>= 1) {
    if (tid < w)
#pragma unroll
      for (int e = 0; e < 4; e++) red[e][tid] += red[e][tid + w];
    __syncthreads();
  }
  if (tid == 0) {
    int o = 0, idx = 0;
#pragma unroll
    for (int e = 0; e < 4; e++) {
      int cnt = red[e][0];
      off[e] = o;
      endp[e] = o + cnt;
      cur[e] = 0;
      int nt = (cnt + 127) >> 7;
      for (int i = 0; i < nt; i++) tmap[1 + idx++] = e | (i << 8);
      o += nt << 7;
    }
    tmap[0] = idx;   // total active m-tiles (<= 131)
  }
}

// ---------------- scatter: token -> (expert bucket, rank), ballot-aggregated --------
__global__ __launch_bounds__(256) void scatter_kernel(const int* __restrict__ einfo,
                                                      const float* __restrict__ w0a,
                                                      const float* __restrict__ w1a,
                                                      const int* __restrict__ off,
                                                      int* __restrict__ cur,
                                                      int* __restrict__ pack,
                                                      float* __restrict__ wlist) {
  int t = blockIdx.x * 256 + threadIdx.x;
  int lane = threadIdx.x & 63;
  int inf = einfo[t];
#pragma unroll
  for (int rank = 0; rank < 2; rank++) {
    int my_e = (rank == 0) ? (inf & 15) : ((inf >> 4) & 15);
    float w = (rank == 0) ? w0a[t] : w1a[t];
#pragma unroll
    for (int e = 0; e < 4; e++) {
      bool p = (my_e == e);
      unsigned long long mask = __ballot(p);
      if (!mask) continue;
      int leader = __ffsll((long long)mask) - 1;
      int base = 0;
      if (lane == leader) base = atomicAdd(&cur[e], (int)__popcll(mask));
      base = __shfl(base, leader, 64);
      if (p) {
        int pos = off[e] + base + (int)__popcll(mask & ((1ULL << lane) - 1ULL));
        pack[pos] = t * 2 + rank;
        wlist[pos] = w;
      }
    }
  }
}

// ---------------- sparse MoE mat1 (BK=32, dbuf, tile-table, XCD-swizzled) ------------
__global__ __launch_bounds__(256) void moe_mat1_kernel(
    const bf16* __restrict__ A, const bf16* __restrict__ Wt,
    const void* __restrict__ bias, size_t boff, bf16* __restrict__ hid,
    const int* __restrict__ off, const int* __restrict__ endp,
    const int* __restrict__ pack, const float* __restrict__ wlist,
    const int* __restrict__ tmap, const int* __restrict__ flag) {
  const int wbf = flag[0];
  int id = blockIdx.x + 8 * blockIdx.y;
  int xcd = id & 7, idq = id >> 3;
  int wx = idq & 7, wy = xcd + 8 * (idq >> 3);
  if (wy >= tmap[0]) return;
  int ent = tmap[1 + wy];
  const int e = ent & 255, mt = ent >> 8;
  const int o = off[e], en = endp[e];
  const int n0 = wx * 128;
  __shared__ bf16 As[2][128][32];
  __shared__ bf16 Bs[2][128][32];
  const int tid = threadIdx.x;
  const int ln = tid & 63, wv = tid >> 6;
  const int m0 = o + mt * 128;
  const int wr = (wv >> 1) * 64, wc = (wv & 1) * 64;
  const int mrow = ln & 15, quad = ln >> 4;
  const int srow = ln >> 2;
  const int skof = (ln & 3) * 8;
  int tokr[2];
#pragma unroll
  for (int j = 0; j < 2; j++) {
    int pos = m0 + 16 * (4 * j + wv) + srow;
    tokr[j] = pack[min(pos, en - 1)] >> 1;
  }
  const size_t wbase = (size_t)e * 1024 * 512;

  auto stage = [&](int pb, int k0) {
#pragma unroll
    for (int j = 0; j < 2; j++)
      gload16(A + (size_t)tokr[j] * 512 + k0 + skof,
              (char*)&As[pb][0][0] + (size_t)(4 * j + wv) * 1024);
#pragma unroll
    for (int j = 0; j < 2; j++) {
      int row = 16 * (4 * j + wv) + srow;
      gload16(Wt + wbase + (size_t)(n0 + row) * 512 + k0 + skof,
              (char*)&Bs[pb][0][0] + (size_t)(4 * j + wv) * 1024);
    }
  };

  f32x4 acc[4][4];
#pragma unroll
  for (int i = 0; i < 4; i++)
#pragma unroll
    for (int j = 0; j < 4; j++) acc[i][j] = (f32x4){0.f, 0.f, 0.f, 0.f};

  stage(0, 0);
  int p = 0;
  for (int k0 = 0; k0 < 512; k0 += 32) {
    __syncthreads();
    if (k0 + 32 < 512) stage(p ^ 1, k0 + 32);
    short8 af[4], bfr[4];
#pragma unroll
    for (int t = 0; t < 4; t++) {
      af[t]  = *(const short8*)&As[p][wr + t * 16 + mrow][quad * 8];
      bfr[t] = *(const short8*)&Bs[p][wc + t * 16 + mrow][quad * 8];
    }
#pragma unroll
    for (int i = 0; i < 4; i++)
#pragma unroll
      for (int j = 0; j < 4; j++)
        acc[i][j] = __builtin_amdgcn_mfma_f32_16x16x32_bf16(af[i], bfr[j], acc[i][j], 0, 0, 0);
    p ^= 1;
  }

#pragma unroll
  for (int ti = 0; ti < 4; ti++) {
#pragma unroll
    for (int r = 0; r < 4; r++) {
      int pos = m0 + wr + ti * 16 + quad * 4 + r;
      float w = (pos < en) ? wlist[pos] : 0.f;
#pragma unroll
      for (int tj = 0; tj < 4; tj++) {
        int ncol = n0 + wc + tj * 16 + mrow;
        float v = acc[ti][tj][r] + ldin(bias, boff + e * 1024 + ncol, wbf);
        hid[(size_t)pos * 1024 + ncol] = __float2bfloat16(fmaxf(v, 0.f) * w);
      }
    }
  }
}

// ---------------- sparse MoE mat2 (BK=32, dbuf, tile-table, XCD-swizzled, z=2) -------
__global__ __launch_bounds__(256) void moe_mat2_kernel(
    const bf16* __restrict__ hid, const bf16* __restrict__ Wt,
    bf16* __restrict__ psl,
    const int* __restrict__ off, const int* __restrict__ endp,
    const int* __restrict__ pack, const int* __restrict__ tmap,
    const int* __restrict__ flag) {
  int id = blockIdx.x + 4 * blockIdx.y;
  int xcd = id & 7, idq = id >> 3;
  int wx = idq & 3, wy = xcd + 8 * (idq >> 2);
  if (wy >= tmap[0]) return;
  int ent = tmap[1 + wy];
  const int e = ent & 255, mt = ent >> 8;
  const int o = off[e], en = endp[e];
  const int n0 = wx * 128;
  __shared__ bf16 As[2][128][32];
  __shared__ bf16 Bs[2][128][32];
  const int tid = threadIdx.x;
  const int ln = tid & 63, wv = tid >> 6;
  const int m0 = o + mt * 128;
  const int wr = (wv >> 1) * 64, wc = (wv & 1) * 64;
  const int mrow = ln & 15, quad = ln >> 4;
  const int srow = ln >> 2;
  const int skof = (ln & 3) * 8;
  const int kbeg = blockIdx.z * 512;
  const size_t wbase = (size_t)e * 512 * 1024;

  auto stage = [&](int pb, int k0) {
#pragma unroll
    for (int j = 0; j < 2; j++) {
      int row = 16 * (4 * j + wv) + srow;
      gload16(hid + (size_t)(m0 + row) * 1024 + k0 + skof,
              (char*)&As[pb][0][0] + (size_t)(4 * j + wv) * 1024);
    }
#pragma unroll
    for (int j = 0; j < 2; j++) {
      int row = 16 * (4 * j + wv) + srow;
      gload16(Wt + wbase + (size_t)(n0 + row) * 1024 + k0 + skof,
              (char*)&Bs[pb][0][0] + (size_t)(4 * j + wv) * 1024);
    }
  };

  f32x4 acc[4][4];
#pragma unroll
  for (int i = 0; i < 4; i++)
#pragma unroll
    for (int j = 0; j < 4; j++) acc[i][j] = (f32x4){0.f, 0.f, 0.f, 0.f};

  stage(0, kbeg);
  int p = 0;
  for (int k0 = kbeg; k0 < kbeg + 512; k0 += 32) {
    __syncthreads();
    if (k0 + 32 < kbeg + 512) stage(p ^ 1, k0 + 32);
    short8 af[4], bfr[4];
#pragma unroll
    for (int t = 0; t < 4; t++) {
      af[t]  = *(const short8*)&As[p][wr + t * 16 + mrow][quad * 8];
      bfr[t] = *(const short8*)&Bs[p][wc + t * 16 + mrow][quad * 8];
    }
#pragma unroll
    for (int i = 0; i < 4; i++)
#pragma unroll
      for (int j = 0; j < 4; j++)
        acc[i][j] = __builtin_amdgcn_mfma_f32_16x16x32_bf16(af[i], bfr[j], acc[i][j], 0, 0, 0);
    p ^= 1;
  }

#pragma unroll
  for (int ti = 0; ti < 4; ti++) {
#pragma unroll
    for (int r = 0; r < 4; r++) {
      int pos = m0 + wr + ti * 16 + quad * 4 + r;
      if (pos < en) {
        int pk = pack[pos];
        int tok = pk >> 1, rank = pk & 1;
        bf16* dst = psl + (size_t)(rank * 2 + blockIdx.z) * T_ * D_ + (size_t)tok * D_;
#pragma unroll
        for (int tj = 0; tj < 4; tj++) {
          int ncol = n0 + wc + tj * 16 + mrow;
          dst[ncol] = __float2bfloat16(acc[ti][tj][r]);
        }
      }
    }
  }
}

// ---------------- head ----------------
__global__ __launch_bounds__(256) void head_kernel(const float* __restrict__ hbuf,
                                                   const void* __restrict__ hw,
                                                   const void* __restrict__ hb,
                                                   void* __restrict__ out,
                                                   const int* __restrict__ flag) {
  const int bf = flag[0];
  int bq = blockIdx.x, tid = threadIdx.x;
  int b = bq / 3, q = bq % 3;
  __shared__ float red[256];
  const float* xr = hbuf + (size_t)(b * S_ + (S_ - 1)) * D_;
  float sacc = xr[tid] * ldin(hw, (size_t)q * D_ + tid, bf)
             + xr[tid + 256] * ldin(hw, (size_t)q * D_ + tid + 256, bf);
  red[tid] = sacc; __syncthreads();
  for (int w = 128; w; w >>= 1) { if (tid < w) red[tid] += red[tid + w]; __syncthreads(); }
  if (tid == 0) {
    float r = red[0] + ldin(hb, q, bf);
    if (bf) ((bf16*)out)[bq] = __float2bfloat16(r);
    else    ((float*)out)[bq] = r;
  }
}

extern "C" void kernel_launch(void* const* d_in, const int* in_sizes, int n_in,
                              void* d_out, int out_size, void* d_ws, size_t ws_size,
                              hipStream_t stream) {
  const void* x    = d_in[0];
  const void* Wp   = d_in[1];
  const void* bp   = d_in[2];
  const void* femb = d_in[3];
  const void* qkvw = d_in[4];
  const void* qkvb = d_in[5];
  const void* ow   = d_in[6];
  const void* ob   = d_in[7];
  const void* g1   = d_in[8];
  const void* be1  = d_in[9];
  const void* gw   = d_in[10];
  const void* gb   = d_in[11];
  const void* ew1  = d_in[12];
  const void* eb1  = d_in[13];
  const void* ew2  = d_in[14];
  const void* eb2  = d_in[15];
  const void* g2   = d_in[16];
  const void* be2  = d_in[17];
  const void* hw   = d_in[18];
  const void* hb   = d_in[19];
  const int*  freq = (const int*)d_in[20];

  // workspace layout: peak ~99.6 MB (within previously proven-safe 101 MB)
  int*   flag  = (int*)d_ws;                        // 64 ints
  int*   off   = flag + 64;                         // 4
  int*   endp  = off + 4;                           // 4
  int*   cur   = endp + 4;                          // 4 (+pad)
  int*   einfo = flag + 128;                        // T ints
  float* w0a   = (float*)(einfo + T_);              // T
  float* w1a   = w0a + T_;                          // T
  int*   pack  = (int*)(w1a + T_);                  // CAP ints
  float* wlist = (float*)(pack + CAP_);             // CAP
  int*   tmap  = (int*)(wlist + CAP_);              // 160 ints (count + tiles)
  float* xn    = (float*)(tmap + 160);              // 65536
  float* h     = xn + 65536;                        // T*D f    (16 MB)
  float* cw    = h + (size_t)T_ * D_;               // T*4
  bf16*  hb16  = (bf16*)(cw + (size_t)T_ * E_);     // T*D bf16 (8 MB)
  bf16*  R     = hb16 + (size_t)T_ * D_;            // alias region
  bf16*  qkvb16 = R;                                // T*3D bf16 (24 MB)
  bf16*  ao    = R + (size_t)T_ * D3_;              // T*D bf16  (8 MB)
  bf16*  hid   = R;                                 // CAP*1024 bf16 (~33 MB)
  bf16*  psl   = R + (size_t)CAP_ * 1024;           // 4x T*D bf16 (32 MB partial slices)
  bf16*  wcvt  = psl + (size_t)4 * T_ * D_;         // 8.4 MB bf16 weight scratch
  // wcvt layout phase 1 (qkv/o-proj): wq [786432], wo [262144]
  // wcvt layout phase 2 (MoE):        we1 [2097152], we2 [2097152]
  bf16*  wq    = wcvt;
  bf16*  wo    = wcvt + (size_t)D3_ * D_;
  bf16*  we1   = wcvt;
  bf16*  we2   = wcvt + (size_t)E_ * 1024 * 512;

  constexpr size_t NQ = (size_t)D3_ * D_;           // 786432
  constexpr size_t NO = (size_t)D_ * D_;            // 262144
  constexpr size_t NE = (size_t)E_ * 1024 * 512;    // 2097152

  detect_kernel<<<1, 64, 0, stream>>>(x, flag);
  instnorm_kernel<<<B_ * F_, 256, 0, stream>>>(x, xn, flag);
  input_proj_kernel<<<(T_ * D_) / 256, 256, 0, stream>>>(xn, Wp, bp, femb, freq, h, hb16, flag);

  for (int l = 0; l < 3; l++) {
    // convert this layer's qkv_w + ow to bf16 scratch (copy if already bf16)
    convw_kernel<<<(NQ + NO) / 2048, 256, 0, stream>>>(
        qkvw, (size_t)l * NQ, NQ, ow, (size_t)l * NO, wcvt, flag);
    // QKV projection -> bf16
    mfma_gemm<3><<<dim3(D3_ / 128, T_ / 128), 256, 0, stream>>>(
        hb16, wq, qkvb, (size_t)l * D3_, qkvb16, D_, D_, D_, D3_, flag);
    attn_kernel<<<B_ * H_ * (S_ / 128), 256, 0, stream>>>(qkvb16, ao);
    // O-projection: split-K=2 -> slices 0,1; fused reduce + bias + LN
    mfma_gemm<0><<<dim3(D_ / 128, T_ / 128, 2), 256, 0, stream>>>(
        ao, wo, nullptr, 0, psl, D_, D_, D_, D_, flag);
    reduce_ln_kernel<<<T_, 256, 0, stream>>>(
        h, hb16, psl, 2, 0, ob, (size_t)l * D_, nullptr, nullptr, 0,
        g1, be1, (size_t)l * D_, flag);
    // gating + routing
    gate_kernel<<<T_ / 4, 256, 0, stream>>>(h, gw, (size_t)l * E_ * D_, gb, (size_t)l * E_,
                                            cw, einfo, w0a, w1a, flag);
    route_scan_kernel<<<1, 256, 0, stream>>>(einfo, off, endp, cur, tmap);
    scatter_kernel<<<T_ / 256, 256, 0, stream>>>(einfo, w0a, w1a, off, cur, pack, wlist);
    // convert this layer's ew1 + ew2 to bf16 scratch (wq/wo dead past here)
    convw_kernel<<<(NE + NE) / 2048, 256, 0, stream>>>(
        ew1, (size_t)l * NE, NE, ew2, (size_t)l * NE, wcvt, flag);
    // sparse expert GEMMs (hid aliases qkv+ao, both dead here)
    moe_mat1_kernel<<<dim3(8, 136), 256, 0, stream>>>(
        hb16, we1, eb1, (size_t)l * E_ * 1024, hid,
        off, endp, pack, wlist, tmap, flag);
    moe_mat2_kernel<<<dim3(4, 136, 2), 256, 0, stream>>>(
        hid, we2, psl, off, endp, pack, tmap, flag);
    reduce_ln_kernel<<<T_, 256, 0, stream>>>(
        h, hb16, psl, 4, 1, nullptr, 0, cw, eb2, (size_t)l * E_ * D_,
        g2, be2, (size_t)l * D_, flag);
  }

  head_kernel<<<24, 256, 0, stream>>>(h, hw, hb, d_out, flag);
}

// Round 3
// 996.838 us; speedup vs baseline: 1.0124x; 1.0124x over previous
//
#include <hip/hip_runtime.h>
#include <hip/hip_bf16.h>
#include <math.h>

typedef __hip_bfloat16 bf16;
typedef __attribute__((ext_vector_type(8))) short short8;   // 8 bf16 (4 VGPRs)
typedef __attribute__((ext_vector_type(4))) float f32x4;

constexpr int B_ = 8, S_ = 1024, F_ = 8, D_ = 512, H_ = 8, E_ = 4;
constexpr int T_  = B_ * S_;       // 8192 tokens
constexpr int D3_ = 3 * D_;        // 1536
constexpr int CAP_ = T_ * 2 + E_ * 128;   // sparse row capacity (top-2, 128-pad/expert)

__device__ __forceinline__ float b2f(bf16 v) { return __bfloat162float(v); }
__device__ __forceinline__ float ldin(const void* p, size_t i, int bf) {
  return bf ? __bfloat162float(((const bf16*)p)[i]) : ((const float*)p)[i];
}
__device__ __forceinline__ void gload16(const void* g, void* l) {
  __builtin_amdgcn_global_load_lds((const __attribute__((address_space(1))) unsigned int*)g,
                                   (__attribute__((address_space(3))) unsigned int*)l, 16, 0, 0);
}

// ---------------- dtype detector ----------------
__global__ void detect_kernel(const void* __restrict__ x, int* __restrict__ flag) {
  if (threadIdx.x == 0 && blockIdx.x == 0) {
    const unsigned short* u = (const unsigned short*)x;
    int c = 0;
    for (int i = 0; i < 256; i += 2) {
      int ex = (u[i] >> 7) & 0xFF;
      if (ex >= 96 && ex <= 144) c++;
    }
    flag[0] = (c >= 64) ? 1 : 0;
  }
}

// ---------------- weight pre-convert: fp32 (or bf16 copy) -> bf16 scratch ----------
// Concatenates two source regions [A: nA elems][B: rest]. 8 elems/thread, vectorized.
__global__ __launch_bounds__(256) void convw_kernel(const void* __restrict__ Asrc, size_t offA,
                                                    size_t nA,
                                                    const void* __restrict__ Bsrc, size_t offB,
                                                    bf16* __restrict__ dst,
                                                    const int* __restrict__ flag) {
  const int bf = flag[0];
  size_t i = ((size_t)blockIdx.x * 256 + threadIdx.x) * 8;
  const void* s = Asrc;
  size_t so = offA + i;
  if (i >= nA) { s = Bsrc; so = offB + (i - nA); }
  if (bf) {
    *(short8*)(dst + i) = *(const short8*)((const bf16*)s + so);
  } else {
    const float* sp = (const float*)s + so;
    short8 v;
#pragma unroll
    for (int u = 0; u < 8; u++) { bf16 t = __float2bfloat16(sp[u]); v[u] = *(short*)&t; }
    *(short8*)(dst + i) = v;
  }
}

// ---------------- instance norm over time axis ----------------
__global__ __launch_bounds__(256) void instnorm_kernel(const void* __restrict__ x,
                                                       float* __restrict__ xn,
                                                       const int* __restrict__ flag) {
  const int bf = flag[0];
  int b = blockIdx.x / F_, f = blockIdx.x % F_;
  int tid = threadIdx.x;
  __shared__ float red[256];
  const int base = b * S_ * F_ + f;
  float s = 0.f;
  for (int j = tid; j < S_; j += 256) s += ldin(x, base + j * F_, bf);
  red[tid] = s; __syncthreads();
  for (int w = 128; w; w >>= 1) { if (tid < w) red[tid] += red[tid + w]; __syncthreads(); }
  float mean = red[0] / S_;
  __syncthreads();
  float v = 0.f;
  for (int j = tid; j < S_; j += 256) { float d = ldin(x, base + j * F_, bf) - mean; v += d * d; }
  red[tid] = v; __syncthreads();
  for (int w = 128; w; w >>= 1) { if (tid < w) red[tid] += red[tid + w]; __syncthreads(); }
  float inv = 1.f / (sqrtf(red[0] / (float)(S_ - 1)) + 1e-5f);
  for (int j = tid; j < S_; j += 256) xn[base + j * F_] = (ldin(x, base + j * F_, bf) - mean) * inv;
}

// ---------------- input projection + freq emb + positional encoding ----------------
__global__ __launch_bounds__(256) void input_proj_kernel(const float* __restrict__ xn,
                                                         const void* __restrict__ Wp,
                                                         const void* __restrict__ bp,
                                                         const void* __restrict__ femb,
                                                         const int* __restrict__ freq_idx,
                                                         float* __restrict__ h,
                                                         bf16* __restrict__ hb16,
                                                         const int* __restrict__ flag) {
  const int bf = flag[0];
  int idx = blockIdx.x * 256 + threadIdx.x;
  int d = idx % D_;
  int t = idx / D_;
  int s = t % S_;
  int fi = freq_idx[0];
  float acc = ldin(bp, d, bf) + ldin(femb, (size_t)fi * D_ + d, bf);
  int i2 = d & ~1;
  const float cexp = -9.2103403719761836f / (float)D_;
  float ang = (float)s * expf((float)i2 * cexp);
  acc += (d & 1) ? cosf(ang) : sinf(ang);
  const float* xr = xn + t * F_;
#pragma unroll
  for (int f = 0; f < F_; f++) acc += xr[f] * ldin(Wp, (size_t)d * F_ + f, bf);
  h[idx] = acc;
  hb16[idx] = __float2bfloat16(acc);
}

// ---------------- dense MFMA GEMM, BK=32, dbuf single-barrier K-loop, XCD swizzle ----
// B operand is pre-converted bf16 (async global_load_lds both operands).
// MODE 3: C bf16 = acc + bias  (QKV). MODE 0: partial bf16 slice per z (O-proj).
// Requires gridDim.y % 8 == 0 for the swizzle.
template <int MODE>
__global__ __launch_bounds__(256) void mfma_gemm(
    const bf16* __restrict__ A, const bf16* __restrict__ Wt,
    const void* __restrict__ bias, size_t boff, void* __restrict__ C_,
    int Kd, int lda, int ldb, int ldc, const int* __restrict__ flag) {
  const int wbf = flag[0];
  __shared__ bf16 As[2][128][32];
  __shared__ bf16 Bs[2][128][32];
  const int tid = threadIdx.x;
  const int ln = tid & 63, wv = tid >> 6;
  int id = blockIdx.x + gridDim.x * blockIdx.y;
  int xcd = id & 7, idq = id >> 3;
  const int n0 = (idq % gridDim.x) * 128;
  const int m0 = (xcd + 8 * (idq / gridDim.x)) * 128;
  const int wr = (wv >> 1) * 64, wc = (wv & 1) * 64;
  const int mrow = ln & 15, quad = ln >> 4;
  const int srow = ln >> 2;
  const int skof = (ln & 3) * 8;
  const int kchunk = Kd / gridDim.z;
  const int kbeg = blockIdx.z * kchunk;
  const int kend = kbeg + kchunk;

  auto stage = [&](int pb, int k0) {
#pragma unroll
    for (int j = 0; j < 2; j++) {
      int row = 16 * (4 * j + wv) + srow;
      gload16(A + (size_t)(m0 + row) * lda + k0 + skof,
              (char*)&As[pb][0][0] + (size_t)(4 * j + wv) * 1024);
    }
#pragma unroll
    for (int j = 0; j < 2; j++) {
      int row = 16 * (4 * j + wv) + srow;
      gload16(Wt + (size_t)(n0 + row) * ldb + k0 + skof,
              (char*)&Bs[pb][0][0] + (size_t)(4 * j + wv) * 1024);
    }
  };

  f32x4 acc[4][4];
#pragma unroll
  for (int i = 0; i < 4; i++)
#pragma unroll
    for (int j = 0; j < 4; j++) acc[i][j] = (f32x4){0.f, 0.f, 0.f, 0.f};

  stage(0, kbeg);
  int p = 0;
  for (int k0 = kbeg; k0 < kend; k0 += 32) {
    __syncthreads();                       // drains prefetch into buf p (vmcnt before barrier)
    if (k0 + 32 < kend) stage(p ^ 1, k0 + 32);   // in flight during compute
    short8 af[4], bfr[4];
#pragma unroll
    for (int t = 0; t < 4; t++) {
      af[t]  = *(const short8*)&As[p][wr + t * 16 + mrow][quad * 8];
      bfr[t] = *(const short8*)&Bs[p][wc + t * 16 + mrow][quad * 8];
    }
#pragma unroll
    for (int i = 0; i < 4; i++)
#pragma unroll
      for (int j = 0; j < 4; j++)
        acc[i][j] = __builtin_amdgcn_mfma_f32_16x16x32_bf16(af[i], bfr[j], acc[i][j], 0, 0, 0);
    p ^= 1;
  }

  bf16* slice = (MODE == 0) ? (bf16*)C_ + (size_t)blockIdx.z * T_ * D_ : (bf16*)C_;
#pragma unroll
  for (int tj = 0; tj < 4; tj++) {
    int n = n0 + wc + tj * 16 + mrow;
    float bv = (MODE == 3) ? ldin(bias, boff + n, wbf) : 0.f;
#pragma unroll
    for (int ti = 0; ti < 4; ti++) {
      int mbase = m0 + wr + ti * 16 + quad * 4;
#pragma unroll
      for (int r = 0; r < 4; r++) {
        int m = mbase + r;
        float v = acc[ti][tj][r];
        slice[(size_t)m * ldc + n] = __float2bfloat16(MODE == 3 ? v + bv : v);
      }
    }
  }
}

// ---------------- MFMA flash attention: 64-query tile, swizzled V transpose --------
// QBLK=64: grid = B*H*16 = 1024 blocks = 4 blocks/CU (grid was the occupancy cap at
// QBLK=128: 512 blocks = 2/CU = 8 waves). Each wave owns 16 q-rows. LDS 27.6 KB.
// Q buffer aliases P buffer (Q fragments register-resident before first P write).
// XCD remap: all 16 q-tiles of one (b,h) on one XCD; 8 K/V panels = 2 MB per L2.
__global__ __launch_bounds__(256) void attn_kernel(const bf16* __restrict__ qkv,
                                                   bf16* __restrict__ o) {
  __shared__ bf16 QP[64][72];    // Q tile, then P tile (aliased)
  __shared__ bf16 Ks[64][72];
  __shared__ bf16 Vt[64][72];    // [d][k ^ swz(d)]
  const int tid = threadIdx.x;
  const int ln = tid & 63, wv = tid >> 6;
  const int mrow = ln & 15, quad = ln >> 4;
  const int id = blockIdx.x;
  const int xcd = id & 7, j = id >> 3;
  const int qt = j & 15;
  const int pr = xcd + 8 * (j >> 4);     // 0..63
  const int hh = pr & 7, b = pr >> 3;
  const int q0 = qt * 64;
  const int sr = tid >> 2;
  const int sg = tid & 3;
  const int sc = sg * 8;

  {
    const bf16* src = qkv + (size_t)(b * S_ + q0 + sr) * D3_ + hh * 64;
    *(short8*)&QP[sr][sc]      = *(const short8*)(src + sc);
    *(short8*)&QP[sr][sc + 32] = *(const short8*)(src + sc + 32);
  }
  __syncthreads();
  short8 aq[2];
  aq[0] = *(const short8*)&QP[wv * 16 + mrow][quad * 8];
  aq[1] = *(const short8*)&QP[wv * 16 + mrow][quad * 8 + 32];

  float m_st[4], l_st[4];
  f32x4 oacc[4];
#pragma unroll
  for (int t = 0; t < 4; t++) {
    m_st[t] = -1e30f; l_st[t] = 0.f;
    oacc[t] = (f32x4){0.f, 0.f, 0.f, 0.f};
  }

  for (int kt = 0; kt < 16; kt++) {
    int k0 = kt * 64;
    __syncthreads();
    {
      const bf16* src = qkv + (size_t)(b * S_ + k0 + sr) * D3_ + D_ + hh * 64;
      *(short8*)&Ks[sr][sc]      = *(const short8*)(src + sc);
      *(short8*)&Ks[sr][sc + 32] = *(const short8*)(src + sc + 32);
    }
    {
      const bf16* src = qkv + (size_t)(b * S_ + k0 + sr) * D3_ + 2 * D_ + hh * 64;
      short8 v0 = *(const short8*)(src + sc);
      short8 v1 = *(const short8*)(src + sc + 32);
      int col0 = sr ^ (sg << 4);
      int col1 = sr ^ (((sg + 4) & 3) << 4);
#pragma unroll
      for (int u = 0; u < 8; u++) {
        *(short*)&Vt[sc + u][col0]      = v0[u];
        *(short*)&Vt[sc + 32 + u][col1] = v1[u];
      }
    }
    __syncthreads();
    f32x4 s[4];
#pragma unroll
    for (int t = 0; t < 4; t++) {
      s[t] = (f32x4){0.f, 0.f, 0.f, 0.f};
#pragma unroll
      for (int ks = 0; ks < 2; ks++) {
        short8 bk = *(const short8*)&Ks[t * 16 + mrow][quad * 8 + ks * 32];
        s[t] = __builtin_amdgcn_mfma_f32_16x16x32_bf16(aq[ks], bk, s[t], 0, 0, 0);
      }
    }
#pragma unroll
    for (int r = 0; r < 4; r++) {
      float rm = fmaxf(fmaxf(s[0][r], s[1][r]), fmaxf(s[2][r], s[3][r])) * 0.125f;
#pragma unroll
      for (int off = 8; off; off >>= 1) rm = fmaxf(rm, __shfl_xor(rm, off, 64));
      float mnew = fmaxf(m_st[r], rm);
      float alpha = __expf(m_st[r] - mnew);
      m_st[r] = mnew;
      float rs = 0.f;
#pragma unroll
      for (int t = 0; t < 4; t++) {
        float p = __expf(s[t][r] * 0.125f - mnew);
        rs += p;
        QP[wv * 16 + quad * 4 + r][t * 16 + mrow] = __float2bfloat16(p);
      }
#pragma unroll
      for (int off = 8; off; off >>= 1) rs += __shfl_xor(rs, off, 64);
      l_st[r] = l_st[r] * alpha + rs;
#pragma unroll
      for (int t = 0; t < 4; t++) oacc[t][r] *= alpha;
    }
    short8 ap[2];
    ap[0] = *(const short8*)&QP[wv * 16 + mrow][quad * 8];
    ap[1] = *(const short8*)&QP[wv * 16 + mrow][quad * 8 + 32];
#pragma unroll
    for (int t = 0; t < 4; t++) {
      int d = t * 16 + mrow;
      int swz = ((d >> 3) & 3) << 4;
#pragma unroll
      for (int ks = 0; ks < 2; ks++) {
        short8 bv = *(const short8*)&Vt[d][(quad * 8 + ks * 32) ^ swz];
        oacc[t] = __builtin_amdgcn_mfma_f32_16x16x32_bf16(ap[ks], bv, oacc[t], 0, 0, 0);
      }
    }
  }
#pragma unroll
  for (int r = 0; r < 4; r++) {
    float inv = 1.f / l_st[r];
    size_t base = (size_t)(b * S_ + q0 + wv * 16 + quad * 4 + r) * D_ + hh * 64;
#pragma unroll
    for (int t = 0; t < 4; t++)
      o[base + t * 16 + mrow] = __float2bfloat16(oacc[t][r] * inv);
  }
}

// ---------------- fused: sum partial slices + bias + residual + LayerNorm ----------
__global__ __launch_bounds__(256) void reduce_ln_kernel(float* __restrict__ h,
                                                        bf16* __restrict__ hb16,
                                                        const bf16* __restrict__ ps,
                                                        int nsl, int mode,
                                                        const void* __restrict__ bias,
                                                        size_t boff,
                                                        const float* __restrict__ cw,
                                                        const void* __restrict__ eb2p,
                                                        size_t e2off,
                                                        const void* __restrict__ g,
                                                        const void* __restrict__ beta,
                                                        size_t off,
                                                        const int* __restrict__ flag) {
  const int bf = flag[0];
  int t = blockIdx.x, tid = threadIdx.x;
  __shared__ float r1[256], r2[256];
  const size_t base = (size_t)t * D_;
  float o0 = 0.f, o1 = 0.f;
  for (int s = 0; s < nsl; s++) {
    o0 += b2f(ps[(size_t)s * T_ * D_ + base + tid]);
    o1 += b2f(ps[(size_t)s * T_ * D_ + base + tid + 256]);
  }
  if (mode == 0) {
    o0 += ldin(bias, boff + tid, bf);
    o1 += ldin(bias, boff + tid + 256, bf);
  } else {
#pragma unroll
    for (int e = 0; e < 4; e++) {
      float w = cw[t * 4 + e];
      o0 += w * ldin(eb2p, e2off + e * D_ + tid, bf);
      o1 += w * ldin(eb2p, e2off + e * D_ + tid + 256, bf);
    }
  }
  float* hr = h + base;
  float v0 = hr[tid] + o0;
  float v1 = hr[tid + 256] + o1;
  r1[tid] = v0 + v1;
  r2[tid] = v0 * v0 + v1 * v1;
  __syncthreads();
  for (int w = 128; w; w >>= 1) { if (tid < w) { r1[tid] += r1[tid + w]; r2[tid] += r2[tid + w]; } __syncthreads(); }
  float mean = r1[0] * (1.f / D_);
  float var  = r2[0] * (1.f / D_) - mean * mean;
  float rstd = rsqrtf(var + 1e-5f);
  float n0 = (v0 - mean) * rstd * ldin(g, off + tid, bf) + ldin(beta, off + tid, bf);
  float n1 = (v1 - mean) * rstd * ldin(g, off + tid + 256, bf) + ldin(beta, off + tid + 256, bf);
  hr[tid] = n0;
  hr[tid + 256] = n1;
  hb16[base + tid] = __float2bfloat16(n0);
  hb16[base + tid + 256] = __float2bfloat16(n1);
}

// ---------------- MoE gating: softmax over E=4, top-2; emits routing info ----------
__global__ __launch_bounds__(256) void gate_kernel(const float* __restrict__ hbuf,
                                                   const void* __restrict__ gw, size_t gwoff,
                                                   const void* __restrict__ gb, size_t gboff,
                                                   float* __restrict__ cw,
                                                   int* __restrict__ einfo,
                                                   float* __restrict__ w0a,
                                                   float* __restrict__ w1a,
                                                   const int* __restrict__ flag) {
  const int bf = flag[0];
  int lane = threadIdx.x & 63, wv = threadIdx.x >> 6;
  int t = blockIdx.x * 4 + wv;
  const float* xr = hbuf + (size_t)t * D_;
  float a[4] = {0, 0, 0, 0};
  for (int d = lane; d < D_; d += 64) {
    float xv = xr[d];
#pragma unroll
    for (int e = 0; e < 4; e++) a[e] += xv * ldin(gw, gwoff + e * D_ + d, bf);
  }
#pragma unroll
  for (int e = 0; e < 4; e++)
    for (int off = 32; off; off >>= 1) a[e] += __shfl_xor(a[e], off, 64);
  if (lane == 0) {
    float lg[4];
#pragma unroll
    for (int e = 0; e < 4; e++) lg[e] = a[e] + ldin(gb, gboff + e, bf);
    float m = fmaxf(fmaxf(lg[0], lg[1]), fmaxf(lg[2], lg[3]));
    float p[4], s = 0.f;
#pragma unroll
    for (int e = 0; e < 4; e++) { p[e] = __expf(lg[e] - m); s += p[e]; }
#pragma unroll
    for (int e = 0; e < 4; e++) p[e] /= s;
    int i0 = 0;
    for (int e = 1; e < 4; e++) if (p[e] > p[i0]) i0 = e;
    int i1 = -1;
    for (int e = 0; e < 4; e++) if (e != i0 && (i1 < 0 || p[e] > p[i1])) i1 = e;
    float s2 = p[i0] + p[i1];
    float ww0 = p[i0] / s2, ww1 = p[i1] / s2;
    float outw[4] = {0, 0, 0, 0};
    outw[i0] = ww0; outw[i1] = ww1;
#pragma unroll
    for (int e = 0; e < 4; e++) cw[t * 4 + e] = outw[e];
    einfo[t] = i0 | (i1 << 4);
    w0a[t] = ww0; w1a[t] = ww1;
  }
}

// ---------------- route scan: counts -> offsets + tile table (1 block) ----------------
__global__ __launch_bounds__(256) void route_scan_kernel(const int* __restrict__ einfo,
                                                         int* __restrict__ off,
                                                         int* __restrict__ endp,
                                                         int* __restrict__ cur,
                                                         int* __restrict__ tmap) {
  __shared__ int red[4][256];
  int tid = threadIdx.x;
  int c[4] = {0, 0, 0, 0};
  for (int t = tid; t < T_; t += 256) {
    int inf = einfo[t];
    c[inf & 15]++;
    c[(inf >> 4) & 15]++;
  }
#pragma unroll
  for (int e = 0; e < 4; e++) red[e][tid] = c[e];
  __syncthreads();
  for (int w = 128; w; w >>= 1) {
    if (tid < w)
#pragma unroll
      for (int e = 0; e < 4; e++) red[e][tid] += red[e][tid + w];
    __syncthreads();
  }
  if (tid == 0) {
    int o = 0, idx = 0;
#pragma unroll
    for (int e = 0; e < 4; e++) {
      int cnt = red[e][0];
      off[e] = o;
      endp[e] = o + cnt;
      cur[e] = 0;
      int nt = (cnt + 127) >> 7;
      for (int i = 0; i < nt; i++) tmap[1 + idx++] = e | (i << 8);
      o += nt << 7;
    }
    tmap[0] = idx;   // total active m-tiles (<= 131)
  }
}

// ---------------- scatter: token -> (expert bucket, rank), ballot-aggregated --------
__global__ __launch_bounds__(256) void scatter_kernel(const int* __restrict__ einfo,
                                                      const float* __restrict__ w0a,
                                                      const float* __restrict__ w1a,
                                                      const int* __restrict__ off,
                                                      int* __restrict__ cur,
                                                      int* __restrict__ pack,
                                                      float* __restrict__ wlist) {
  int t = blockIdx.x * 256 + threadIdx.x;
  int lane = threadIdx.x & 63;
  int inf = einfo[t];
#pragma unroll
  for (int rank = 0; rank < 2; rank++) {
    int my_e = (rank == 0) ? (inf & 15) : ((inf >> 4) & 15);
    float w = (rank == 0) ? w0a[t] : w1a[t];
#pragma unroll
    for (int e = 0; e < 4; e++) {
      bool p = (my_e == e);
      unsigned long long mask = __ballot(p);
      if (!mask) continue;
      int leader = __ffsll((long long)mask) - 1;
      int base = 0;
      if (lane == leader) base = atomicAdd(&cur[e], (int)__popcll(mask));
      base = __shfl(base, leader, 64);
      if (p) {
        int pos = off[e] + base + (int)__popcll(mask & ((1ULL << lane) - 1ULL));
        pack[pos] = t * 2 + rank;
        wlist[pos] = w;
      }
    }
  }
}

// ---------------- sparse MoE mat1 (BK=32, dbuf, tile-table, XCD-swizzled) ------------
__global__ __launch_bounds__(256) void moe_mat1_kernel(
    const bf16* __restrict__ A, const bf16* __restrict__ Wt,
    const void* __restrict__ bias, size_t boff, bf16* __restrict__ hid,
    const int* __restrict__ off, const int* __restrict__ endp,
    const int* __restrict__ pack, const float* __restrict__ wlist,
    const int* __restrict__ tmap, const int* __restrict__ flag) {
  const int wbf = flag[0];
  int id = blockIdx.x + 8 * blockIdx.y;
  int xcd = id & 7, idq = id >> 3;
  int wx = idq & 7, wy = xcd + 8 * (idq >> 3);
  if (wy >= tmap[0]) return;
  int ent = tmap[1 + wy];
  const int e = ent & 255, mt = ent >> 8;
  const int o = off[e], en = endp[e];
  const int n0 = wx * 128;
  __shared__ bf16 As[2][128][32];
  __shared__ bf16 Bs[2][128][32];
  const int tid = threadIdx.x;
  const int ln = tid & 63, wv = tid >> 6;
  const int m0 = o + mt * 128;
  const int wr = (wv >> 1) * 64, wc = (wv & 1) * 64;
  const int mrow = ln & 15, quad = ln >> 4;
  const int srow = ln >> 2;
  const int skof = (ln & 3) * 8;
  int tokr[2];
#pragma unroll
  for (int j = 0; j < 2; j++) {
    int pos = m0 + 16 * (4 * j + wv) + srow;
    tokr[j] = pack[min(pos, en - 1)] >> 1;
  }
  const size_t wbase = (size_t)e * 1024 * 512;

  auto stage = [&](int pb, int k0) {
#pragma unroll
    for (int j = 0; j < 2; j++)
      gload16(A + (size_t)tokr[j] * 512 + k0 + skof,
              (char*)&As[pb][0][0] + (size_t)(4 * j + wv) * 1024);
#pragma unroll
    for (int j = 0; j < 2; j++) {
      int row = 16 * (4 * j + wv) + srow;
      gload16(Wt + wbase + (size_t)(n0 + row) * 512 + k0 + skof,
              (char*)&Bs[pb][0][0] + (size_t)(4 * j + wv) * 1024);
    }
  };

  f32x4 acc[4][4];
#pragma unroll
  for (int i = 0; i < 4; i++)
#pragma unroll
    for (int j = 0; j < 4; j++) acc[i][j] = (f32x4){0.f, 0.f, 0.f, 0.f};

  stage(0, 0);
  int p = 0;
  for (int k0 = 0; k0 < 512; k0 += 32) {
    __syncthreads();
    if (k0 + 32 < 512) stage(p ^ 1, k0 + 32);
    short8 af[4], bfr[4];
#pragma unroll
    for (int t = 0; t < 4; t++) {
      af[t]  = *(const short8*)&As[p][wr + t * 16 + mrow][quad * 8];
      bfr[t] = *(const short8*)&Bs[p][wc + t * 16 + mrow][quad * 8];
    }
#pragma unroll
    for (int i = 0; i < 4; i++)
#pragma unroll
      for (int j = 0; j < 4; j++)
        acc[i][j] = __builtin_amdgcn_mfma_f32_16x16x32_bf16(af[i], bfr[j], acc[i][j], 0, 0, 0);
    p ^= 1;
  }

#pragma unroll
  for (int ti = 0; ti < 4; ti++) {
#pragma unroll
    for (int r = 0; r < 4; r++) {
      int pos = m0 + wr + ti * 16 + quad * 4 + r;
      float w = (pos < en) ? wlist[pos] : 0.f;
#pragma unroll
      for (int tj = 0; tj < 4; tj++) {
        int ncol = n0 + wc + tj * 16 + mrow;
        float v = acc[ti][tj][r] + ldin(bias, boff + e * 1024 + ncol, wbf);
        hid[(size_t)pos * 1024 + ncol] = __float2bfloat16(fmaxf(v, 0.f) * w);
      }
    }
  }
}

// ---------------- sparse MoE mat2 (BK=32, dbuf, tile-table, XCD-swizzled, z=2) -------
__global__ __launch_bounds__(256) void moe_mat2_kernel(
    const bf16* __restrict__ hid, const bf16* __restrict__ Wt,
    bf16* __restrict__ psl,
    const int* __restrict__ off, const int* __restrict__ endp,
    const int* __restrict__ pack, const int* __restrict__ tmap,
    const int* __restrict__ flag) {
  int id = blockIdx.x + 4 * blockIdx.y;
  int xcd = id & 7, idq = id >> 3;
  int wx = idq & 3, wy = xcd + 8 * (idq >> 2);
  if (wy >= tmap[0]) return;
  int ent = tmap[1 + wy];
  const int e = ent & 255, mt = ent >> 8;
  const int o = off[e], en = endp[e];
  const int n0 = wx * 128;
  __shared__ bf16 As[2][128][32];
  __shared__ bf16 Bs[2][128][32];
  const int tid = threadIdx.x;
  const int ln = tid & 63, wv = tid >> 6;
  const int m0 = o + mt * 128;
  const int wr = (wv >> 1) * 64, wc = (wv & 1) * 64;
  const int mrow = ln & 15, quad = ln >> 4;
  const int srow = ln >> 2;
  const int skof = (ln & 3) * 8;
  const int kbeg = blockIdx.z * 512;
  const size_t wbase = (size_t)e * 512 * 1024;

  auto stage = [&](int pb, int k0) {
#pragma unroll
    for (int j = 0; j < 2; j++) {
      int row = 16 * (4 * j + wv) + srow;
      gload16(hid + (size_t)(m0 + row) * 1024 + k0 + skof,
              (char*)&As[pb][0][0] + (size_t)(4 * j + wv) * 1024);
    }
#pragma unroll
    for (int j = 0; j < 2; j++) {
      int row = 16 * (4 * j + wv) + srow;
      gload16(Wt + wbase + (size_t)(n0 + row) * 1024 + k0 + skof,
              (char*)&Bs[pb][0][0] + (size_t)(4 * j + wv) * 1024);
    }
  };

  f32x4 acc[4][4];
#pragma unroll
  for (int i = 0; i < 4; i++)
#pragma unroll
    for (int j = 0; j < 4; j++) acc[i][j] = (f32x4){0.f, 0.f, 0.f, 0.f};

  stage(0, kbeg);
  int p = 0;
  for (int k0 = kbeg; k0 < kbeg + 512; k0 += 32) {
    __syncthreads();
    if (k0 + 32 < kbeg + 512) stage(p ^ 1, k0 + 32);
    short8 af[4], bfr[4];
#pragma unroll
    for (int t = 0; t < 4; t++) {
      af[t]  = *(const short8*)&As[p][wr + t * 16 + mrow][quad * 8];
      bfr[t] = *(const short8*)&Bs[p][wc + t * 16 + mrow][quad * 8];
    }
#pragma unroll
    for (int i = 0; i < 4; i++)
#pragma unroll
      for (int j = 0; j < 4; j++)
        acc[i][j] = __builtin_amdgcn_mfma_f32_16x16x32_bf16(af[i], bfr[j], acc[i][j], 0, 0, 0);
    p ^= 1;
  }

#pragma unroll
  for (int ti = 0; ti < 4; ti++) {
#pragma unroll
    for (int r = 0; r < 4; r++) {
      int pos = m0 + wr + ti * 16 + quad * 4 + r;
      if (pos < en) {
        int pk = pack[pos];
        int tok = pk >> 1, rank = pk & 1;
        bf16* dst = psl + (size_t)(rank * 2 + blockIdx.z) * T_ * D_ + (size_t)tok * D_;
#pragma unroll
        for (int tj = 0; tj < 4; tj++) {
          int ncol = n0 + wc + tj * 16 + mrow;
          dst[ncol] = __float2bfloat16(acc[ti][tj][r]);
        }
      }
    }
  }
}

// ---------------- head ----------------
__global__ __launch_bounds__(256) void head_kernel(const float* __restrict__ hbuf,
                                                   const void* __restrict__ hw,
                                                   const void* __restrict__ hb,
                                                   void* __restrict__ out,
                                                   const int* __restrict__ flag) {
  const int bf = flag[0];
  int bq = blockIdx.x, tid = threadIdx.x;
  int b = bq / 3, q = bq % 3;
  __shared__ float red[256];
  const float* xr = hbuf + (size_t)(b * S_ + (S_ - 1)) * D_;
  float sacc = xr[tid] * ldin(hw, (size_t)q * D_ + tid, bf)
             + xr[tid + 256] * ldin(hw, (size_t)q * D_ + tid + 256, bf);
  red[tid] = sacc; __syncthreads();
  for (int w = 128; w; w >>= 1) { if (tid < w) red[tid] += red[tid + w]; __syncthreads(); }
  if (tid == 0) {
    float r = red[0] + ldin(hb, q, bf);
    if (bf) ((bf16*)out)[bq] = __float2bfloat16(r);
    else    ((float*)out)[bq] = r;
  }
}

extern "C" void kernel_launch(void* const* d_in, const int* in_sizes, int n_in,
                              void* d_out, int out_size, void* d_ws, size_t ws_size,
                              hipStream_t stream) {
  const void* x    = d_in[0];
  const void* Wp   = d_in[1];
  const void* bp   = d_in[2];
  const void* femb = d_in[3];
  const void* qkvw = d_in[4];
  const void* qkvb = d_in[5];
  const void* ow   = d_in[6];
  const void* ob   = d_in[7];
  const void* g1   = d_in[8];
  const void* be1  = d_in[9];
  const void* gw   = d_in[10];
  const void* gb   = d_in[11];
  const void* ew1  = d_in[12];
  const void* eb1  = d_in[13];
  const void* ew2  = d_in[14];
  const void* eb2  = d_in[15];
  const void* g2   = d_in[16];
  const void* be2  = d_in[17];
  const void* hw   = d_in[18];
  const void* hb   = d_in[19];
  const int*  freq = (const int*)d_in[20];

  // workspace layout: peak ~99.6 MB (within previously proven-safe 101 MB)
  int*   flag  = (int*)d_ws;                        // 64 ints
  int*   off   = flag + 64;                         // 4
  int*   endp  = off + 4;                           // 4
  int*   cur   = endp + 4;                          // 4 (+pad)
  int*   einfo = flag + 128;                        // T ints
  float* w0a   = (float*)(einfo + T_);              // T
  float* w1a   = w0a + T_;                          // T
  int*   pack  = (int*)(w1a + T_);                  // CAP ints
  float* wlist = (float*)(pack + CAP_);             // CAP
  int*   tmap  = (int*)(wlist + CAP_);              // 160 ints (count + tiles)
  float* xn    = (float*)(tmap + 160);              // 65536
  float* h     = xn + 65536;                        // T*D f    (16 MB)
  float* cw    = h + (size_t)T_ * D_;               // T*4
  bf16*  hb16  = (bf16*)(cw + (size_t)T_ * E_);     // T*D bf16 (8 MB)
  bf16*  R     = hb16 + (size_t)T_ * D_;            // alias region
  bf16*  qkvb16 = R;                                // T*3D bf16 (24 MB)
  bf16*  ao    = R + (size_t)T_ * D3_;              // T*D bf16  (8 MB)
  bf16*  hid   = R;                                 // CAP*1024 bf16 (~33 MB)
  bf16*  psl   = R + (size_t)CAP_ * 1024;           // 4x T*D bf16 (32 MB partial slices)
  bf16*  wcvt  = psl + (size_t)4 * T_ * D_;         // 8.4 MB bf16 weight scratch
  // wcvt layout phase 1 (qkv/o-proj): wq [786432], wo [262144]
  // wcvt layout phase 2 (MoE):        we1 [2097152], we2 [2097152]
  bf16*  wq    = wcvt;
  bf16*  wo    = wcvt + (size_t)D3_ * D_;
  bf16*  we1   = wcvt;
  bf16*  we2   = wcvt + (size_t)E_ * 1024 * 512;

  constexpr size_t NQ = (size_t)D3_ * D_;           // 786432
  constexpr size_t NO = (size_t)D_ * D_;            // 262144
  constexpr size_t NE = (size_t)E_ * 1024 * 512;    // 2097152

  detect_kernel<<<1, 64, 0, stream>>>(x, flag);
  instnorm_kernel<<<B_ * F_, 256, 0, stream>>>(x, xn, flag);
  input_proj_kernel<<<(T_ * D_) / 256, 256, 0, stream>>>(xn, Wp, bp, femb, freq, h, hb16, flag);

  for (int l = 0; l < 3; l++) {
    // convert this layer's qkv_w + ow to bf16 scratch (copy if already bf16)
    convw_kernel<<<(NQ + NO) / 2048, 256, 0, stream>>>(
        qkvw, (size_t)l * NQ, NQ, ow, (size_t)l * NO, wcvt, flag);
    // QKV projection -> bf16
    mfma_gemm<3><<<dim3(D3_ / 128, T_ / 128), 256, 0, stream>>>(
        hb16, wq, qkvb, (size_t)l * D3_, qkvb16, D_, D_, D_, D3_, flag);
    attn_kernel<<<B_ * H_ * (S_ / 64), 256, 0, stream>>>(qkvb16, ao);
    // O-projection: split-K=2 -> slices 0,1; fused reduce + bias + LN
    mfma_gemm<0><<<dim3(D_ / 128, T_ / 128, 2), 256, 0, stream>>>(
        ao, wo, nullptr, 0, psl, D_, D_, D_, D_, flag);
    reduce_ln_kernel<<<T_, 256, 0, stream>>>(
        h, hb16, psl, 2, 0, ob, (size_t)l * D_, nullptr, nullptr, 0,
        g1, be1, (size_t)l * D_, flag);
    // gating + routing
    gate_kernel<<<T_ / 4, 256, 0, stream>>>(h, gw, (size_t)l * E_ * D_, gb, (size_t)l * E_,
                                            cw, einfo, w0a, w1a, flag);
    route_scan_kernel<<<1, 256, 0, stream>>>(einfo, off, endp, cur, tmap);
    scatter_kernel<<<T_ / 256, 256, 0, stream>>>(einfo, w0a, w1a, off, cur, pack, wlist);
    // convert this layer's ew1 + ew2 to bf16 scratch (wq/wo dead past here)
    convw_kernel<<<(NE + NE) / 2048, 256, 0, stream>>>(
        ew1, (size_t)l * NE, NE, ew2, (size_t)l * NE, wcvt, flag);
    // sparse expert GEMMs (hid aliases qkv+ao, both dead here)
    moe_mat1_kernel<<<dim3(8, 136), 256, 0, stream>>>(
        hb16, we1, eb1, (size_t)l * E_ * 1024, hid,
        off, endp, pack, wlist, tmap, flag);
    moe_mat2_kernel<<<dim3(4, 136, 2), 256, 0, stream>>>(
        hid, we2, psl, off, endp, pack, tmap, flag);
    reduce_ln_kernel<<<T_, 256, 0, stream>>>(
        h, hb16, psl, 4, 1, nullptr, 0, cw, eb2, (size_t)l * E_ * D_,
        g2, be2, (size_t)l * D_, flag);
  }

  head_kernel<<<24, 256, 0, stream>>>(h, hw, hb, d_out, flag);
}

// Round 4
// 939.437 us; speedup vs baseline: 1.0743x; 1.0611x over previous
//
#include <hip/hip_runtime.h>
#include <hip/hip_bf16.h>
#include <math.h>

typedef __hip_bfloat16 bf16;
typedef __attribute__((ext_vector_type(8))) short short8;   // 8 bf16 (4 VGPRs)
typedef __attribute__((ext_vector_type(4))) short s4v;      // 4 bf16 (8 bytes)
typedef __attribute__((ext_vector_type(4))) float f32x4;

constexpr int B_ = 8, S_ = 1024, F_ = 8, D_ = 512, H_ = 8, E_ = 4;
constexpr int T_  = B_ * S_;       // 8192 tokens
constexpr int D3_ = 3 * D_;        // 1536
constexpr int CAP_ = T_ * 2 + E_ * 128;   // sparse row capacity (top-2, 128-pad/expert)

__device__ __forceinline__ float b2f(bf16 v) { return __bfloat162float(v); }
__device__ __forceinline__ float ldin(const void* p, size_t i, int bf) {
  return bf ? __bfloat162float(((const bf16*)p)[i]) : ((const float*)p)[i];
}
__device__ __forceinline__ void gload16(const void* g, void* l) {
  __builtin_amdgcn_global_load_lds((const __attribute__((address_space(1))) unsigned int*)g,
                                   (__attribute__((address_space(3))) unsigned int*)l, 16, 0, 0);
}

// ---------------- dtype detector ----------------
__global__ void detect_kernel(const void* __restrict__ x, int* __restrict__ flag) {
  if (threadIdx.x == 0 && blockIdx.x == 0) {
    const unsigned short* u = (const unsigned short*)x;
    int c = 0;
    for (int i = 0; i < 256; i += 2) {
      int ex = (u[i] >> 7) & 0xFF;
      if (ex >= 96 && ex <= 144) c++;
    }
    flag[0] = (c >= 64) ? 1 : 0;
  }
}

// ---------------- weight pre-convert: fp32 (or bf16 copy) -> bf16 scratch ----------
// Concatenates two source regions [A: nA elems][B: rest]. 8 elems/thread, vectorized.
__global__ __launch_bounds__(256) void convw_kernel(const void* __restrict__ Asrc, size_t offA,
                                                    size_t nA,
                                                    const void* __restrict__ Bsrc, size_t offB,
                                                    bf16* __restrict__ dst,
                                                    const int* __restrict__ flag) {
  const int bf = flag[0];
  size_t i = ((size_t)blockIdx.x * 256 + threadIdx.x) * 8;
  const void* s = Asrc;
  size_t so = offA + i;
  if (i >= nA) { s = Bsrc; so = offB + (i - nA); }
  if (bf) {
    *(short8*)(dst + i) = *(const short8*)((const bf16*)s + so);
  } else {
    const float* sp = (const float*)s + so;
    short8 v;
#pragma unroll
    for (int u = 0; u < 8; u++) { bf16 t = __float2bfloat16(sp[u]); v[u] = *(short*)&t; }
    *(short8*)(dst + i) = v;
  }
}

// ---------------- instance norm over time axis ----------------
__global__ __launch_bounds__(256) void instnorm_kernel(const void* __restrict__ x,
                                                       float* __restrict__ xn,
                                                       const int* __restrict__ flag) {
  const int bf = flag[0];
  int b = blockIdx.x / F_, f = blockIdx.x % F_;
  int tid = threadIdx.x;
  __shared__ float red[256];
  const int base = b * S_ * F_ + f;
  float s = 0.f;
  for (int j = tid; j < S_; j += 256) s += ldin(x, base + j * F_, bf);
  red[tid] = s; __syncthreads();
  for (int w = 128; w; w >>= 1) { if (tid < w) red[tid] += red[tid + w]; __syncthreads(); }
  float mean = red[0] / S_;
  __syncthreads();
  float v = 0.f;
  for (int j = tid; j < S_; j += 256) { float d = ldin(x, base + j * F_, bf) - mean; v += d * d; }
  red[tid] = v; __syncthreads();
  for (int w = 128; w; w >>= 1) { if (tid < w) red[tid] += red[tid + w]; __syncthreads(); }
  float inv = 1.f / (sqrtf(red[0] / (float)(S_ - 1)) + 1e-5f);
  for (int j = tid; j < S_; j += 256) xn[base + j * F_] = (ldin(x, base + j * F_, bf) - mean) * inv;
}

// ---------------- input projection + freq emb + positional encoding ----------------
__global__ __launch_bounds__(256) void input_proj_kernel(const float* __restrict__ xn,
                                                         const void* __restrict__ Wp,
                                                         const void* __restrict__ bp,
                                                         const void* __restrict__ femb,
                                                         const int* __restrict__ freq_idx,
                                                         float* __restrict__ h,
                                                         bf16* __restrict__ hb16,
                                                         const int* __restrict__ flag) {
  const int bf = flag[0];
  int idx = blockIdx.x * 256 + threadIdx.x;
  int d = idx % D_;
  int t = idx / D_;
  int s = t % S_;
  int fi = freq_idx[0];
  float acc = ldin(bp, d, bf) + ldin(femb, (size_t)fi * D_ + d, bf);
  int i2 = d & ~1;
  const float cexp = -9.2103403719761836f / (float)D_;
  float ang = (float)s * expf((float)i2 * cexp);
  acc += (d & 1) ? cosf(ang) : sinf(ang);
  const float* xr = xn + t * F_;
#pragma unroll
  for (int f = 0; f < F_; f++) acc += xr[f] * ldin(Wp, (size_t)d * F_ + f, bf);
  h[idx] = acc;
  hb16[idx] = __float2bfloat16(acc);
}

// ---------------- dense MFMA GEMM, BK=32, dbuf single-barrier K-loop, XCD swizzle ----
// B operand is pre-converted bf16 (async global_load_lds both operands).
// MODE 3: C bf16 = acc + bias  (QKV). MODE 0: partial bf16 slice per z (O-proj).
// Requires gridDim.y % 8 == 0 for the swizzle.
template <int MODE>
__global__ __launch_bounds__(256) void mfma_gemm(
    const bf16* __restrict__ A, const bf16* __restrict__ Wt,
    const void* __restrict__ bias, size_t boff, void* __restrict__ C_,
    int Kd, int lda, int ldb, int ldc, const int* __restrict__ flag) {
  const int wbf = flag[0];
  __shared__ bf16 As[2][128][32];
  __shared__ bf16 Bs[2][128][32];
  const int tid = threadIdx.x;
  const int ln = tid & 63, wv = tid >> 6;
  int id = blockIdx.x + gridDim.x * blockIdx.y;
  int xcd = id & 7, idq = id >> 3;
  const int n0 = (idq % gridDim.x) * 128;
  const int m0 = (xcd + 8 * (idq / gridDim.x)) * 128;
  const int wr = (wv >> 1) * 64, wc = (wv & 1) * 64;
  const int mrow = ln & 15, quad = ln >> 4;
  const int srow = ln >> 2;
  const int skof = (ln & 3) * 8;
  const int kchunk = Kd / gridDim.z;
  const int kbeg = blockIdx.z * kchunk;
  const int kend = kbeg + kchunk;

  auto stage = [&](int pb, int k0) {
#pragma unroll
    for (int j = 0; j < 2; j++) {
      int row = 16 * (4 * j + wv) + srow;
      gload16(A + (size_t)(m0 + row) * lda + k0 + skof,
              (char*)&As[pb][0][0] + (size_t)(4 * j + wv) * 1024);
    }
#pragma unroll
    for (int j = 0; j < 2; j++) {
      int row = 16 * (4 * j + wv) + srow;
      gload16(Wt + (size_t)(n0 + row) * ldb + k0 + skof,
              (char*)&Bs[pb][0][0] + (size_t)(4 * j + wv) * 1024);
    }
  };

  f32x4 acc[4][4];
#pragma unroll
  for (int i = 0; i < 4; i++)
#pragma unroll
    for (int j = 0; j < 4; j++) acc[i][j] = (f32x4){0.f, 0.f, 0.f, 0.f};

  stage(0, kbeg);
  int p = 0;
  for (int k0 = kbeg; k0 < kend; k0 += 32) {
    __syncthreads();                       // drains prefetch into buf p (vmcnt before barrier)
    if (k0 + 32 < kend) stage(p ^ 1, k0 + 32);   // in flight during compute
    short8 af[4], bfr[4];
#pragma unroll
    for (int t = 0; t < 4; t++) {
      af[t]  = *(const short8*)&As[p][wr + t * 16 + mrow][quad * 8];
      bfr[t] = *(const short8*)&Bs[p][wc + t * 16 + mrow][quad * 8];
    }
#pragma unroll
    for (int i = 0; i < 4; i++)
#pragma unroll
      for (int j = 0; j < 4; j++)
        acc[i][j] = __builtin_amdgcn_mfma_f32_16x16x32_bf16(af[i], bfr[j], acc[i][j], 0, 0, 0);
    p ^= 1;
  }

  bf16* slice = (MODE == 0) ? (bf16*)C_ + (size_t)blockIdx.z * T_ * D_ : (bf16*)C_;
#pragma unroll
  for (int tj = 0; tj < 4; tj++) {
    int n = n0 + wc + tj * 16 + mrow;
    float bv = (MODE == 3) ? ldin(bias, boff + n, wbf) : 0.f;
#pragma unroll
    for (int ti = 0; ti < 4; ti++) {
      int mbase = m0 + wr + ti * 16 + quad * 4;
#pragma unroll
      for (int r = 0; r < 4; r++) {
        int m = mbase + r;
        float v = acc[ti][tj][r];
        slice[(size_t)m * ldc + n] = __float2bfloat16(MODE == 3 ? v + bv : v);
      }
    }
  }
}

// ---------------- MFMA flash attention: 64-query tile, swapped QK^T softmax --------
// sT = mfma(K_frag, Q_frag): lane holds the full 64-wide P row for q = lane&15
// (k = t*16 + quad*4 + r). Row max/sum = in-register reduce + 2 shfl_xor (quad group).
// P spill = 4x ds_write_b64 (was 16 scalar b16); m/l state scalar per lane.
// 32 shfls/iter -> 8. PV and V-transpose unchanged. P region is wave-private.
__global__ __launch_bounds__(256) void attn_kernel(const bf16* __restrict__ qkv,
                                                   bf16* __restrict__ o) {
  __shared__ bf16 QP[64][72];    // Q tile, then P tile (aliased; rows wv*16.. wave-private)
  __shared__ bf16 Ks[64][72];
  __shared__ bf16 Vt[64][72];    // [d][k ^ swz(d)]
  const int tid = threadIdx.x;
  const int ln = tid & 63, wv = tid >> 6;
  const int mrow = ln & 15, quad = ln >> 4;
  const int id = blockIdx.x;
  const int xcd = id & 7, j = id >> 3;
  const int qt = j & 15;
  const int pr = xcd + 8 * (j >> 4);     // 0..63
  const int hh = pr & 7, b = pr >> 3;
  const int q0 = qt * 64;
  const int sr = tid >> 2;
  const int sg = tid & 3;
  const int sc = sg * 8;

  {
    const bf16* src = qkv + (size_t)(b * S_ + q0 + sr) * D3_ + hh * 64;
    *(short8*)&QP[sr][sc]      = *(const short8*)(src + sc);
    *(short8*)&QP[sr][sc + 32] = *(const short8*)(src + sc + 32);
  }
  __syncthreads();
  short8 aq[2];
  aq[0] = *(const short8*)&QP[wv * 16 + mrow][quad * 8];
  aq[1] = *(const short8*)&QP[wv * 16 + mrow][quad * 8 + 32];

  float m_st = -1e30f, l_st = 0.f;     // state for q = mrow (replicated across quad group)
  f32x4 oacc[4];
#pragma unroll
  for (int t = 0; t < 4; t++) oacc[t] = (f32x4){0.f, 0.f, 0.f, 0.f};

  for (int kt = 0; kt < 16; kt++) {
    int k0 = kt * 64;
    __syncthreads();
    {
      const bf16* src = qkv + (size_t)(b * S_ + k0 + sr) * D3_ + D_ + hh * 64;
      *(short8*)&Ks[sr][sc]      = *(const short8*)(src + sc);
      *(short8*)&Ks[sr][sc + 32] = *(const short8*)(src + sc + 32);
    }
    {
      const bf16* src = qkv + (size_t)(b * S_ + k0 + sr) * D3_ + 2 * D_ + hh * 64;
      short8 v0 = *(const short8*)(src + sc);
      short8 v1 = *(const short8*)(src + sc + 32);
      int col0 = sr ^ (sg << 4);
      int col1 = sr ^ (((sg + 4) & 3) << 4);
#pragma unroll
      for (int u = 0; u < 8; u++) {
        *(short*)&Vt[sc + u][col0]      = v0[u];
        *(short*)&Vt[sc + 32 + u][col1] = v1[u];
      }
    }
    __syncthreads();
    // swapped QK^T: sT[t] row = k_local (quad*4+r), col = q (mrow)
    f32x4 s[4];
#pragma unroll
    for (int t = 0; t < 4; t++) {
      s[t] = (f32x4){0.f, 0.f, 0.f, 0.f};
#pragma unroll
      for (int ks = 0; ks < 2; ks++) {
        short8 bk = *(const short8*)&Ks[t * 16 + mrow][quad * 8 + ks * 32];
        s[t] = __builtin_amdgcn_mfma_f32_16x16x32_bf16(bk, aq[ks], s[t], 0, 0, 0);
      }
    }
    // in-register row stats for q = mrow over this lane's 16 k-values
    float rm = s[0][0];
#pragma unroll
    for (int t = 0; t < 4; t++)
#pragma unroll
      for (int r = 0; r < 4; r++) rm = fmaxf(rm, s[t][r]);
    rm *= 0.125f;
    rm = fmaxf(rm, __shfl_xor(rm, 16, 64));
    rm = fmaxf(rm, __shfl_xor(rm, 32, 64));
    float mnew = fmaxf(m_st, rm);
    float alpha = __expf(m_st - mnew);
    m_st = mnew;
    float rs = 0.f;
#pragma unroll
    for (int t = 0; t < 4; t++) {
      s4v pk;
#pragma unroll
      for (int r = 0; r < 4; r++) {
        float p = __expf(s[t][r] * 0.125f - mnew);
        rs += p;
        bf16 tb = __float2bfloat16(p);
        pk[r] = *(short*)&tb;
      }
      *(s4v*)&QP[wv * 16 + mrow][t * 16 + quad * 4] = pk;  // 4 contiguous k
    }
    rs += __shfl_xor(rs, 16, 64);
    rs += __shfl_xor(rs, 32, 64);
    l_st = l_st * alpha + rs;
    // rescale oacc rows (row q_local = quad*4+r; alpha lives at lane q_local)
    float af4[4];
#pragma unroll
    for (int r = 0; r < 4; r++) af4[r] = __shfl(alpha, quad * 4 + r, 64);
#pragma unroll
    for (int t = 0; t < 4; t++)
#pragma unroll
      for (int r = 0; r < 4; r++) oacc[t][r] *= af4[r];
    // PV
    short8 ap[2];
    ap[0] = *(const short8*)&QP[wv * 16 + mrow][quad * 8];
    ap[1] = *(const short8*)&QP[wv * 16 + mrow][quad * 8 + 32];
#pragma unroll
    for (int t = 0; t < 4; t++) {
      int d = t * 16 + mrow;
      int swz = ((d >> 3) & 3) << 4;
#pragma unroll
      for (int ks = 0; ks < 2; ks++) {
        short8 bv = *(const short8*)&Vt[d][(quad * 8 + ks * 32) ^ swz];
        oacc[t] = __builtin_amdgcn_mfma_f32_16x16x32_bf16(ap[ks], bv, oacc[t], 0, 0, 0);
      }
    }
  }
  float linv[4];
#pragma unroll
  for (int r = 0; r < 4; r++) linv[r] = 1.f / __shfl(l_st, quad * 4 + r, 64);
#pragma unroll
  for (int r = 0; r < 4; r++) {
    size_t base = (size_t)(b * S_ + q0 + wv * 16 + quad * 4 + r) * D_ + hh * 64;
#pragma unroll
    for (int t = 0; t < 4; t++)
      o[base + t * 16 + mrow] = __float2bfloat16(oacc[t][r] * linv[r]);
  }
}

// ---------------- fused: sum partial slices + bias + residual + LayerNorm ----------
__global__ __launch_bounds__(256) void reduce_ln_kernel(float* __restrict__ h,
                                                        bf16* __restrict__ hb16,
                                                        const bf16* __restrict__ ps,
                                                        int nsl, int mode,
                                                        const void* __restrict__ bias,
                                                        size_t boff,
                                                        const float* __restrict__ cw,
                                                        const void* __restrict__ eb2p,
                                                        size_t e2off,
                                                        const void* __restrict__ g,
                                                        const void* __restrict__ beta,
                                                        size_t off,
                                                        const int* __restrict__ flag) {
  const int bf = flag[0];
  int t = blockIdx.x, tid = threadIdx.x;
  __shared__ float r1[256], r2[256];
  const size_t base = (size_t)t * D_;
  float o0 = 0.f, o1 = 0.f;
  for (int s = 0; s < nsl; s++) {
    o0 += b2f(ps[(size_t)s * T_ * D_ + base + tid]);
    o1 += b2f(ps[(size_t)s * T_ * D_ + base + tid + 256]);
  }
  if (mode == 0) {
    o0 += ldin(bias, boff + tid, bf);
    o1 += ldin(bias, boff + tid + 256, bf);
  } else {
#pragma unroll
    for (int e = 0; e < 4; e++) {
      float w = cw[t * 4 + e];
      o0 += w * ldin(eb2p, e2off + e * D_ + tid, bf);
      o1 += w * ldin(eb2p, e2off + e * D_ + tid + 256, bf);
    }
  }
  float* hr = h + base;
  float v0 = hr[tid] + o0;
  float v1 = hr[tid + 256] + o1;
  r1[tid] = v0 + v1;
  r2[tid] = v0 * v0 + v1 * v1;
  __syncthreads();
  for (int w = 128; w; w >>= 1) { if (tid < w) { r1[tid] += r1[tid + w]; r2[tid] += r2[tid + w]; } __syncthreads(); }
  float mean = r1[0] * (1.f / D_);
  float var  = r2[0] * (1.f / D_) - mean * mean;
  float rstd = rsqrtf(var + 1e-5f);
  float n0 = (v0 - mean) * rstd * ldin(g, off + tid, bf) + ldin(beta, off + tid, bf);
  float n1 = (v1 - mean) * rstd * ldin(g, off + tid + 256, bf) + ldin(beta, off + tid + 256, bf);
  hr[tid] = n0;
  hr[tid + 256] = n1;
  hb16[base + tid] = __float2bfloat16(n0);
  hb16[base + tid + 256] = __float2bfloat16(n1);
}

// ---------------- MoE gating: softmax over E=4, top-2; emits routing info ----------
__global__ __launch_bounds__(256) void gate_kernel(const float* __restrict__ hbuf,
                                                   const void* __restrict__ gw, size_t gwoff,
                                                   const void* __restrict__ gb, size_t gboff,
                                                   float* __restrict__ cw,
                                                   int* __restrict__ einfo,
                                                   float* __restrict__ w0a,
                                                   float* __restrict__ w1a,
                                                   const int* __restrict__ flag) {
  const int bf = flag[0];
  int lane = threadIdx.x & 63, wv = threadIdx.x >> 6;
  int t = blockIdx.x * 4 + wv;
  const float* xr = hbuf + (size_t)t * D_;
  float a[4] = {0, 0, 0, 0};
  for (int d = lane; d < D_; d += 64) {
    float xv = xr[d];
#pragma unroll
    for (int e = 0; e < 4; e++) a[e] += xv * ldin(gw, gwoff + e * D_ + d, bf);
  }
#pragma unroll
  for (int e = 0; e < 4; e++)
    for (int off = 32; off; off >>= 1) a[e] += __shfl_xor(a[e], off, 64);
  if (lane == 0) {
    float lg[4];
#pragma unroll
    for (int e = 0; e < 4; e++) lg[e] = a[e] + ldin(gb, gboff + e, bf);
    float m = fmaxf(fmaxf(lg[0], lg[1]), fmaxf(lg[2], lg[3]));
    float p[4], s = 0.f;
#pragma unroll
    for (int e = 0; e < 4; e++) { p[e] = __expf(lg[e] - m); s += p[e]; }
#pragma unroll
    for (int e = 0; e < 4; e++) p[e] /= s;
    int i0 = 0;
    for (int e = 1; e < 4; e++) if (p[e] > p[i0]) i0 = e;
    int i1 = -1;
    for (int e = 0; e < 4; e++) if (e != i0 && (i1 < 0 || p[e] > p[i1])) i1 = e;
    float s2 = p[i0] + p[i1];
    float ww0 = p[i0] / s2, ww1 = p[i1] / s2;
    float outw[4] = {0, 0, 0, 0};
    outw[i0] = ww0; outw[i1] = ww1;
#pragma unroll
    for (int e = 0; e < 4; e++) cw[t * 4 + e] = outw[e];
    einfo[t] = i0 | (i1 << 4);
    w0a[t] = ww0; w1a[t] = ww1;
  }
}

// ---------------- route scan: counts -> offsets + tile table (1 block) ----------------
__global__ __launch_bounds__(256) void route_scan_kernel(const int* __restrict__ einfo,
                                                         int* __restrict__ off,
                                                         int* __restrict__ endp,
                                                         int* __restrict__ cur,
                                                         int* __restrict__ tmap) {
  __shared__ int red[4][256];
  int tid = threadIdx.x;
  int c[4] = {0, 0, 0, 0};
  for (int t = tid; t < T_; t += 256) {
    int inf = einfo[t];
    c[inf & 15]++;
    c[(inf >> 4) & 15]++;
  }
#pragma unroll
  for (int e = 0; e < 4; e++) red[e][tid] = c[e];
  __syncthreads();
  for (int w = 128; w; w >>= 1) {
    if (tid < w)
#pragma unroll
      for (int e = 0; e < 4; e++) red[e][tid] += red[e][tid + w];
    __syncthreads();
  }
  if (tid == 0) {
    int o = 0, idx = 0;
#pragma unroll
    for (int e = 0; e < 4; e++) {
      int cnt = red[e][0];
      off[e] = o;
      endp[e] = o + cnt;
      cur[e] = 0;
      int nt = (cnt + 127) >> 7;
      for (int i = 0; i < nt; i++) tmap[1 + idx++] = e | (i << 8);
      o += nt << 7;
    }
    tmap[0] = idx;   // total active m-tiles (<= 131)
  }
}

// ---------------- scatter: token -> (expert bucket, rank), ballot-aggregated --------
__global__ __launch_bounds__(256) void scatter_kernel(const int* __restrict__ einfo,
                                                      const float* __restrict__ w0a,
                                                      const float* __restrict__ w1a,
                                                      const int* __restrict__ off,
                                                      int* __restrict__ cur,
                                                      int* __restrict__ pack,
                                                      float* __restrict__ wlist) {
  int t = blockIdx.x * 256 + threadIdx.x;
  int lane = threadIdx.x & 63;
  int inf = einfo[t];
#pragma unroll
  for (int rank = 0; rank < 2; rank++) {
    int my_e = (rank == 0) ? (inf & 15) : ((inf >> 4) & 15);
    float w = (rank == 0) ? w0a[t] : w1a[t];
#pragma unroll
    for (int e = 0; e < 4; e++) {
      bool p = (my_e == e);
      unsigned long long mask = __ballot(p);
      if (!mask) continue;
      int leader = __ffsll((long long)mask) - 1;
      int base = 0;
      if (lane == leader) base = atomicAdd(&cur[e], (int)__popcll(mask));
      base = __shfl(base, leader, 64);
      if (p) {
        int pos = off[e] + base + (int)__popcll(mask & ((1ULL << lane) - 1ULL));
        pack[pos] = t * 2 + rank;
        wlist[pos] = w;
      }
    }
  }
}

// ---------------- sparse MoE mat1 (BK=32, dbuf, tile-table, XCD-swizzled) ------------
__global__ __launch_bounds__(256) void moe_mat1_kernel(
    const bf16* __restrict__ A, const bf16* __restrict__ Wt,
    const void* __restrict__ bias, size_t boff, bf16* __restrict__ hid,
    const int* __restrict__ off, const int* __restrict__ endp,
    const int* __restrict__ pack, const float* __restrict__ wlist,
    const int* __restrict__ tmap, const int* __restrict__ flag) {
  const int wbf = flag[0];
  int id = blockIdx.x + 8 * blockIdx.y;
  int xcd = id & 7, idq = id >> 3;
  int wx = idq & 7, wy = xcd + 8 * (idq >> 3);
  if (wy >= tmap[0]) return;
  int ent = tmap[1 + wy];
  const int e = ent & 255, mt = ent >> 8;
  const int o = off[e], en = endp[e];
  const int n0 = wx * 128;
  __shared__ bf16 As[2][128][32];
  __shared__ bf16 Bs[2][128][32];
  const int tid = threadIdx.x;
  const int ln = tid & 63, wv = tid >> 6;
  const int m0 = o + mt * 128;
  const int wr = (wv >> 1) * 64, wc = (wv & 1) * 64;
  const int mrow = ln & 15, quad = ln >> 4;
  const int srow = ln >> 2;
  const int skof = (ln & 3) * 8;
  int tokr[2];
#pragma unroll
  for (int j = 0; j < 2; j++) {
    int pos = m0 + 16 * (4 * j + wv) + srow;
    tokr[j] = pack[min(pos, en - 1)] >> 1;
  }
  const size_t wbase = (size_t)e * 1024 * 512;

  auto stage = [&](int pb, int k0) {
#pragma unroll
    for (int j = 0; j < 2; j++)
      gload16(A + (size_t)tokr[j] * 512 + k0 + skof,
              (char*)&As[pb][0][0] + (size_t)(4 * j + wv) * 1024);
#pragma unroll
    for (int j = 0; j < 2; j++) {
      int row = 16 * (4 * j + wv) + srow;
      gload16(Wt + wbase + (size_t)(n0 + row) * 512 + k0 + skof,
              (char*)&Bs[pb][0][0] + (size_t)(4 * j + wv) * 1024);
    }
  };

  f32x4 acc[4][4];
#pragma unroll
  for (int i = 0; i < 4; i++)
#pragma unroll
    for (int j = 0; j < 4; j++) acc[i][j] = (f32x4){0.f, 0.f, 0.f, 0.f};

  stage(0, 0);
  int p = 0;
  for (int k0 = 0; k0 < 512; k0 += 32) {
    __syncthreads();
    if (k0 + 32 < 512) stage(p ^ 1, k0 + 32);
    short8 af[4], bfr[4];
#pragma unroll
    for (int t = 0; t < 4; t++) {
      af[t]  = *(const short8*)&As[p][wr + t * 16 + mrow][quad * 8];
      bfr[t] = *(const short8*)&Bs[p][wc + t * 16 + mrow][quad * 8];
    }
#pragma unroll
    for (int i = 0; i < 4; i++)
#pragma unroll
      for (int j = 0; j < 4; j++)
        acc[i][j] = __builtin_amdgcn_mfma_f32_16x16x32_bf16(af[i], bfr[j], acc[i][j], 0, 0, 0);
    p ^= 1;
  }

#pragma unroll
  for (int ti = 0; ti < 4; ti++) {
#pragma unroll
    for (int r = 0; r < 4; r++) {
      int pos = m0 + wr + ti * 16 + quad * 4 + r;
      float w = (pos < en) ? wlist[pos] : 0.f;
#pragma unroll
      for (int tj = 0; tj < 4; tj++) {
        int ncol = n0 + wc + tj * 16 + mrow;
        float v = acc[ti][tj][r] + ldin(bias, boff + e * 1024 + ncol, wbf);
        hid[(size_t)pos * 1024 + ncol] = __float2bfloat16(fmaxf(v, 0.f) * w);
      }
    }
  }
}

// ---------------- sparse MoE mat2 (BK=32, dbuf, tile-table, XCD-swizzled, z=2) -------
__global__ __launch_bounds__(256) void moe_mat2_kernel(
    const bf16* __restrict__ hid, const bf16* __restrict__ Wt,
    bf16* __restrict__ psl,
    const int* __restrict__ off, const int* __restrict__ endp,
    const int* __restrict__ pack, const int* __restrict__ tmap,
    const int* __restrict__ flag) {
  int id = blockIdx.x + 4 * blockIdx.y;
  int xcd = id & 7, idq = id >> 3;
  int wx = idq & 3, wy = xcd + 8 * (idq >> 2);
  if (wy >= tmap[0]) return;
  int ent = tmap[1 + wy];
  const int e = ent & 255, mt = ent >> 8;
  const int o = off[e], en = endp[e];
  const int n0 = wx * 128;
  __shared__ bf16 As[2][128][32];
  __shared__ bf16 Bs[2][128][32];
  const int tid = threadIdx.x;
  const int ln = tid & 63, wv = tid >> 6;
  const int m0 = o + mt * 128;
  const int wr = (wv >> 1) * 64, wc = (wv & 1) * 64;
  const int mrow = ln & 15, quad = ln >> 4;
  const int srow = ln >> 2;
  const int skof = (ln & 3) * 8;
  const int kbeg = blockIdx.z * 512;
  const size_t wbase = (size_t)e * 512 * 1024;

  auto stage = [&](int pb, int k0) {
#pragma unroll
    for (int j = 0; j < 2; j++) {
      int row = 16 * (4 * j + wv) + srow;
      gload16(hid + (size_t)(m0 + row) * 1024 + k0 + skof,
              (char*)&As[pb][0][0] + (size_t)(4 * j + wv) * 1024);
    }
#pragma unroll
    for (int j = 0; j < 2; j++) {
      int row = 16 * (4 * j + wv) + srow;
      gload16(Wt + wbase + (size_t)(n0 + row) * 1024 + k0 + skof,
              (char*)&Bs[pb][0][0] + (size_t)(4 * j + wv) * 1024);
    }
  };

  f32x4 acc[4][4];
#pragma unroll
  for (int i = 0; i < 4; i++)
#pragma unroll
    for (int j = 0; j < 4; j++) acc[i][j] = (f32x4){0.f, 0.f, 0.f, 0.f};

  stage(0, kbeg);
  int p = 0;
  for (int k0 = kbeg; k0 < kbeg + 512; k0 += 32) {
    __syncthreads();
    if (k0 + 32 < kbeg + 512) stage(p ^ 1, k0 + 32);
    short8 af[4], bfr[4];
#pragma unroll
    for (int t = 0; t < 4; t++) {
      af[t]  = *(const short8*)&As[p][wr + t * 16 + mrow][quad * 8];
      bfr[t] = *(const short8*)&Bs[p][wc + t * 16 + mrow][quad * 8];
    }
#pragma unroll
    for (int i = 0; i < 4; i++)
#pragma unroll
      for (int j = 0; j < 4; j++)
        acc[i][j] = __builtin_amdgcn_mfma_f32_16x16x32_bf16(af[i], bfr[j], acc[i][j], 0, 0, 0);
    p ^= 1;
  }

#pragma unroll
  for (int ti = 0; ti < 4; ti++) {
#pragma unroll
    for (int r = 0; r < 4; r++) {
      int pos = m0 + wr + ti * 16 + quad * 4 + r;
      if (pos < en) {
        int pk = pack[pos];
        int tok = pk >> 1, rank = pk & 1;
        bf16* dst = psl + (size_t)(rank * 2 + blockIdx.z) * T_ * D_ + (size_t)tok * D_;
#pragma unroll
        for (int tj = 0; tj < 4; tj++) {
          int ncol = n0 + wc + tj * 16 + mrow;
          dst[ncol] = __float2bfloat16(acc[ti][tj][r]);
        }
      }
    }
  }
}

// ---------------- head ----------------
__global__ __launch_bounds__(256) void head_kernel(const float* __restrict__ hbuf,
                                                   const void* __restrict__ hw,
                                                   const void* __restrict__ hb,
                                                   void* __restrict__ out,
                                                   const int* __restrict__ flag) {
  const int bf = flag[0];
  int bq = blockIdx.x, tid = threadIdx.x;
  int b = bq / 3, q = bq % 3;
  __shared__ float red[256];
  const float* xr = hbuf + (size_t)(b * S_ + (S_ - 1)) * D_;
  float sacc = xr[tid] * ldin(hw, (size_t)q * D_ + tid, bf)
             + xr[tid + 256] * ldin(hw, (size_t)q * D_ + tid + 256, bf);
  red[tid] = sacc; __syncthreads();
  for (int w = 128; w; w >>= 1) { if (tid < w) red[tid] += red[tid + w]; __syncthreads(); }
  if (tid == 0) {
    float r = red[0] + ldin(hb, q, bf);
    if (bf) ((bf16*)out)[bq] = __float2bfloat16(r);
    else    ((float*)out)[bq] = r;
  }
}

extern "C" void kernel_launch(void* const* d_in, const int* in_sizes, int n_in,
                              void* d_out, int out_size, void* d_ws, size_t ws_size,
                              hipStream_t stream) {
  const void* x    = d_in[0];
  const void* Wp   = d_in[1];
  const void* bp   = d_in[2];
  const void* femb = d_in[3];
  const void* qkvw = d_in[4];
  const void* qkvb = d_in[5];
  const void* ow   = d_in[6];
  const void* ob   = d_in[7];
  const void* g1   = d_in[8];
  const void* be1  = d_in[9];
  const void* gw   = d_in[10];
  const void* gb   = d_in[11];
  const void* ew1  = d_in[12];
  const void* eb1  = d_in[13];
  const void* ew2  = d_in[14];
  const void* eb2  = d_in[15];
  const void* g2   = d_in[16];
  const void* be2  = d_in[17];
  const void* hw   = d_in[18];
  const void* hb   = d_in[19];
  const int*  freq = (const int*)d_in[20];

  // workspace layout: peak ~99.6 MB (within previously proven-safe 101 MB)
  int*   flag  = (int*)d_ws;                        // 64 ints
  int*   off   = flag + 64;                         // 4
  int*   endp  = off + 4;                           // 4
  int*   cur   = endp + 4;                          // 4 (+pad)
  int*   einfo = flag + 128;                        // T ints
  float* w0a   = (float*)(einfo + T_);              // T
  float* w1a   = w0a + T_;                          // T
  int*   pack  = (int*)(w1a + T_);                  // CAP ints
  float* wlist = (float*)(pack + CAP_);             // CAP
  int*   tmap  = (int*)(wlist + CAP_);              // 160 ints (count + tiles)
  float* xn    = (float*)(tmap + 160);              // 65536
  float* h     = xn + 65536;                        // T*D f    (16 MB)
  float* cw    = h + (size_t)T_ * D_;               // T*4
  bf16*  hb16  = (bf16*)(cw + (size_t)T_ * E_);     // T*D bf16 (8 MB)
  bf16*  R     = hb16 + (size_t)T_ * D_;            // alias region
  bf16*  qkvb16 = R;                                // T*3D bf16 (24 MB)
  bf16*  ao    = R + (size_t)T_ * D3_;              // T*D bf16  (8 MB)
  bf16*  hid   = R;                                 // CAP*1024 bf16 (~33 MB)
  bf16*  psl   = R + (size_t)CAP_ * 1024;           // 4x T*D bf16 (32 MB partial slices)
  bf16*  wcvt  = psl + (size_t)4 * T_ * D_;         // 8.4 MB bf16 weight scratch
  // wcvt layout phase 1 (qkv/o-proj): wq [786432], wo [262144]
  // wcvt layout phase 2 (MoE):        we1 [2097152], we2 [2097152]
  bf16*  wq    = wcvt;
  bf16*  wo    = wcvt + (size_t)D3_ * D_;
  bf16*  we1   = wcvt;
  bf16*  we2   = wcvt + (size_t)E_ * 1024 * 512;

  constexpr size_t NQ = (size_t)D3_ * D_;           // 786432
  constexpr size_t NO = (size_t)D_ * D_;            // 262144
  constexpr size_t NE = (size_t)E_ * 1024 * 512;    // 2097152

  detect_kernel<<<1, 64, 0, stream>>>(x, flag);
  instnorm_kernel<<<B_ * F_, 256, 0, stream>>>(x, xn, flag);
  input_proj_kernel<<<(T_ * D_) / 256, 256, 0, stream>>>(xn, Wp, bp, femb, freq, h, hb16, flag);

  for (int l = 0; l < 3; l++) {
    // convert this layer's qkv_w + ow to bf16 scratch (copy if already bf16)
    convw_kernel<<<(NQ + NO) / 2048, 256, 0, stream>>>(
        qkvw, (size_t)l * NQ, NQ, ow, (size_t)l * NO, wcvt, flag);
    // QKV projection -> bf16
    mfma_gemm<3><<<dim3(D3_ / 128, T_ / 128), 256, 0, stream>>>(
        hb16, wq, qkvb, (size_t)l * D3_, qkvb16, D_, D_, D_, D3_, flag);
    attn_kernel<<<B_ * H_ * (S_ / 64), 256, 0, stream>>>(qkvb16, ao);
    // O-projection: split-K=2 -> slices 0,1; fused reduce + bias + LN
    mfma_gemm<0><<<dim3(D_ / 128, T_ / 128, 2), 256, 0, stream>>>(
        ao, wo, nullptr, 0, psl, D_, D_, D_, D_, flag);
    reduce_ln_kernel<<<T_, 256, 0, stream>>>(
        h, hb16, psl, 2, 0, ob, (size_t)l * D_, nullptr, nullptr, 0,
        g1, be1, (size_t)l * D_, flag);
    // gating + routing
    gate_kernel<<<T_ / 4, 256, 0, stream>>>(h, gw, (size_t)l * E_ * D_, gb, (size_t)l * E_,
                                            cw, einfo, w0a, w1a, flag);
    route_scan_kernel<<<1, 256, 0, stream>>>(einfo, off, endp, cur, tmap);
    scatter_kernel<<<T_ / 256, 256, 0, stream>>>(einfo, w0a, w1a, off, cur, pack, wlist);
    // convert this layer's ew1 + ew2 to bf16 scratch (wq/wo dead past here)
    convw_kernel<<<(NE + NE) / 2048, 256, 0, stream>>>(
        ew1, (size_t)l * NE, NE, ew2, (size_t)l * NE, wcvt, flag);
    // sparse expert GEMMs (hid aliases qkv+ao, both dead here)
    moe_mat1_kernel<<<dim3(8, 136), 256, 0, stream>>>(
        hb16, we1, eb1, (size_t)l * E_ * 1024, hid,
        off, endp, pack, wlist, tmap, flag);
    moe_mat2_kernel<<<dim3(4, 136, 2), 256, 0, stream>>>(
        hid, we2, psl, off, endp, pack, tmap, flag);
    reduce_ln_kernel<<<T_, 256, 0, stream>>>(
        h, hb16, psl, 4, 1, nullptr, 0, cw, eb2, (size_t)l * E_ * D_,
        g2, be2, (size_t)l * D_, flag);
  }

  head_kernel<<<24, 256, 0, stream>>>(h, hw, hb, d_out, flag);
}

// Round 5
// 936.843 us; speedup vs baseline: 1.0772x; 1.0028x over previous
//
#include <hip/hip_runtime.h>
#include <hip/hip_bf16.h>
#include <math.h>

typedef __hip_bfloat16 bf16;
typedef __attribute__((ext_vector_type(8))) short short8;   // 8 bf16 (4 VGPRs)
typedef __attribute__((ext_vector_type(4))) short s4v;      // 4 bf16 (8 bytes)
typedef __attribute__((ext_vector_type(4))) float f32x4;

constexpr int B_ = 8, S_ = 1024, F_ = 8, D_ = 512, H_ = 8, E_ = 4;
constexpr int T_  = B_ * S_;       // 8192 tokens
constexpr int D3_ = 3 * D_;        // 1536
constexpr int CAP_ = T_ * 2 + E_ * 128;   // sparse row capacity (top-2, 128-pad/expert)

__device__ __forceinline__ float b2f(bf16 v) { return __bfloat162float(v); }
__device__ __forceinline__ float ldin(const void* p, size_t i, int bf) {
  return bf ? __bfloat162float(((const bf16*)p)[i]) : ((const float*)p)[i];
}
__device__ __forceinline__ void gload16(const void* g, void* l) {
  __builtin_amdgcn_global_load_lds((const __attribute__((address_space(1))) unsigned int*)g,
                                   (__attribute__((address_space(3))) unsigned int*)l, 16, 0, 0);
}

// ---------------- dtype detector ----------------
__global__ void detect_kernel(const void* __restrict__ x, int* __restrict__ flag) {
  if (threadIdx.x == 0 && blockIdx.x == 0) {
    const unsigned short* u = (const unsigned short*)x;
    int c = 0;
    for (int i = 0; i < 256; i += 2) {
      int ex = (u[i] >> 7) & 0xFF;
      if (ex >= 96 && ex <= 144) c++;
    }
    flag[0] = (c >= 64) ? 1 : 0;
  }
}

// ---------------- weight pre-convert: fp32 (or bf16 copy) -> bf16 scratch ----------
// Concatenates two source regions [A: nA elems][B: rest]. 8 elems/thread, vectorized.
__global__ __launch_bounds__(256) void convw_kernel(const void* __restrict__ Asrc, size_t offA,
                                                    size_t nA,
                                                    const void* __restrict__ Bsrc, size_t offB,
                                                    bf16* __restrict__ dst,
                                                    const int* __restrict__ flag) {
  const int bf = flag[0];
  size_t i = ((size_t)blockIdx.x * 256 + threadIdx.x) * 8;
  const void* s = Asrc;
  size_t so = offA + i;
  if (i >= nA) { s = Bsrc; so = offB + (i - nA); }
  if (bf) {
    *(short8*)(dst + i) = *(const short8*)((const bf16*)s + so);
  } else {
    const float* sp = (const float*)s + so;
    short8 v;
#pragma unroll
    for (int u = 0; u < 8; u++) { bf16 t = __float2bfloat16(sp[u]); v[u] = *(short*)&t; }
    *(short8*)(dst + i) = v;
  }
}

// ---------------- instance norm over time axis ----------------
__global__ __launch_bounds__(256) void instnorm_kernel(const void* __restrict__ x,
                                                       float* __restrict__ xn,
                                                       const int* __restrict__ flag) {
  const int bf = flag[0];
  int b = blockIdx.x / F_, f = blockIdx.x % F_;
  int tid = threadIdx.x;
  __shared__ float red[256];
  const int base = b * S_ * F_ + f;
  float s = 0.f;
  for (int j = tid; j < S_; j += 256) s += ldin(x, base + j * F_, bf);
  red[tid] = s; __syncthreads();
  for (int w = 128; w; w >>= 1) { if (tid < w) red[tid] += red[tid + w]; __syncthreads(); }
  float mean = red[0] / S_;
  __syncthreads();
  float v = 0.f;
  for (int j = tid; j < S_; j += 256) { float d = ldin(x, base + j * F_, bf) - mean; v += d * d; }
  red[tid] = v; __syncthreads();
  for (int w = 128; w; w >>= 1) { if (tid < w) red[tid] += red[tid + w]; __syncthreads(); }
  float inv = 1.f / (sqrtf(red[0] / (float)(S_ - 1)) + 1e-5f);
  for (int j = tid; j < S_; j += 256) xn[base + j * F_] = (ldin(x, base + j * F_, bf) - mean) * inv;
}

// ---------------- positional-encoding + bias + freq-emb add-table [S][D] -----------
// One thread per (s, even/odd d pair): one expf + one sincosf, no lane divergence.
// Replaces 4.2M divergent trig calls in input_proj with 262K fused ones (8x fewer,
// batch-invariant). Table lives in the R alias region (dead until QKV GEMM).
__global__ __launch_bounds__(256) void pe_kernel(const void* __restrict__ bp,
                                                 const void* __restrict__ femb,
                                                 const int* __restrict__ freq_idx,
                                                 float* __restrict__ addtab,
                                                 const int* __restrict__ flag) {
  const int bf = flag[0];
  int idx = blockIdx.x * 256 + threadIdx.x;      // S*D/2 threads
  int dp = idx & (D_ / 2 - 1);
  int s  = idx / (D_ / 2);
  int d0 = dp * 2;
  int fi = freq_idx[0];
  const float cexp = -9.2103403719761836f / (float)D_;
  float ang = (float)s * expf((float)d0 * cexp);
  float sv, cv;
  sincosf(ang, &sv, &cv);
  addtab[(size_t)s * D_ + d0]     = sv + ldin(bp, d0, bf)     + ldin(femb, (size_t)fi * D_ + d0, bf);
  addtab[(size_t)s * D_ + d0 + 1] = cv + ldin(bp, d0 + 1, bf) + ldin(femb, (size_t)fi * D_ + d0 + 1, bf);
}

// ---------------- input projection: xn @ Wp^T + addtab (no trig) -------------------
__global__ __launch_bounds__(256) void input_proj_kernel(const float* __restrict__ xn,
                                                         const void* __restrict__ Wp,
                                                         const float* __restrict__ addtab,
                                                         float* __restrict__ h,
                                                         bf16* __restrict__ hb16,
                                                         const int* __restrict__ flag) {
  const int bf = flag[0];
  int idx = blockIdx.x * 256 + threadIdx.x;
  int d = idx % D_;
  int t = idx / D_;
  int s = t % S_;
  float acc = addtab[(size_t)s * D_ + d];
  const float* xr = xn + t * F_;
#pragma unroll
  for (int f = 0; f < F_; f++) acc += xr[f] * ldin(Wp, (size_t)d * F_ + f, bf);
  h[idx] = acc;
  hb16[idx] = __float2bfloat16(acc);
}

// ---------------- dense MFMA GEMM, BK=32, dbuf single-barrier K-loop, XCD swizzle ----
// B operand is pre-converted bf16 (async global_load_lds both operands).
// MODE 3: C bf16 = acc + bias  (QKV). MODE 0: partial bf16 slice per z (O-proj).
// Requires gridDim.y % 8 == 0 for the swizzle.
template <int MODE>
__global__ __launch_bounds__(256) void mfma_gemm(
    const bf16* __restrict__ A, const bf16* __restrict__ Wt,
    const void* __restrict__ bias, size_t boff, void* __restrict__ C_,
    int Kd, int lda, int ldb, int ldc, const int* __restrict__ flag) {
  const int wbf = flag[0];
  __shared__ bf16 As[2][128][32];
  __shared__ bf16 Bs[2][128][32];
  const int tid = threadIdx.x;
  const int ln = tid & 63, wv = tid >> 6;
  int id = blockIdx.x + gridDim.x * blockIdx.y;
  int xcd = id & 7, idq = id >> 3;
  const int n0 = (idq % gridDim.x) * 128;
  const int m0 = (xcd + 8 * (idq / gridDim.x)) * 128;
  const int wr = (wv >> 1) * 64, wc = (wv & 1) * 64;
  const int mrow = ln & 15, quad = ln >> 4;
  const int srow = ln >> 2;
  const int skof = (ln & 3) * 8;
  const int kchunk = Kd / gridDim.z;
  const int kbeg = blockIdx.z * kchunk;
  const int kend = kbeg + kchunk;

  auto stage = [&](int pb, int k0) {
#pragma unroll
    for (int j = 0; j < 2; j++) {
      int row = 16 * (4 * j + wv) + srow;
      gload16(A + (size_t)(m0 + row) * lda + k0 + skof,
              (char*)&As[pb][0][0] + (size_t)(4 * j + wv) * 1024);
    }
#pragma unroll
    for (int j = 0; j < 2; j++) {
      int row = 16 * (4 * j + wv) + srow;
      gload16(Wt + (size_t)(n0 + row) * ldb + k0 + skof,
              (char*)&Bs[pb][0][0] + (size_t)(4 * j + wv) * 1024);
    }
  };

  f32x4 acc[4][4];
#pragma unroll
  for (int i = 0; i < 4; i++)
#pragma unroll
    for (int j = 0; j < 4; j++) acc[i][j] = (f32x4){0.f, 0.f, 0.f, 0.f};

  stage(0, kbeg);
  int p = 0;
  for (int k0 = kbeg; k0 < kend; k0 += 32) {
    __syncthreads();                       // drains prefetch into buf p (vmcnt before barrier)
    if (k0 + 32 < kend) stage(p ^ 1, k0 + 32);   // in flight during compute
    short8 af[4], bfr[4];
#pragma unroll
    for (int t = 0; t < 4; t++) {
      af[t]  = *(const short8*)&As[p][wr + t * 16 + mrow][quad * 8];
      bfr[t] = *(const short8*)&Bs[p][wc + t * 16 + mrow][quad * 8];
    }
#pragma unroll
    for (int i = 0; i < 4; i++)
#pragma unroll
      for (int j = 0; j < 4; j++)
        acc[i][j] = __builtin_amdgcn_mfma_f32_16x16x32_bf16(af[i], bfr[j], acc[i][j], 0, 0, 0);
    p ^= 1;
  }

  bf16* slice = (MODE == 0) ? (bf16*)C_ + (size_t)blockIdx.z * T_ * D_ : (bf16*)C_;
#pragma unroll
  for (int tj = 0; tj < 4; tj++) {
    int n = n0 + wc + tj * 16 + mrow;
    float bv = (MODE == 3) ? ldin(bias, boff + n, wbf) : 0.f;
#pragma unroll
    for (int ti = 0; ti < 4; ti++) {
      int mbase = m0 + wr + ti * 16 + quad * 4;
#pragma unroll
      for (int r = 0; r < 4; r++) {
        int m = mbase + r;
        float v = acc[ti][tj][r];
        slice[(size_t)m * ldc + n] = __float2bfloat16(MODE == 3 ? v + bv : v);
      }
    }
  }
}

// ---------------- MFMA flash attention: 64-query tile, swapped QK^T softmax --------
// sT = mfma(K_frag, Q_frag): lane holds the full 64-wide P row for q = lane&15
// (k = t*16 + quad*4 + r). Row max/sum = in-register reduce + 2 shfl_xor (quad group).
// P spill = 4x ds_write_b64; m/l state scalar per lane. P region is wave-private.
__global__ __launch_bounds__(256) void attn_kernel(const bf16* __restrict__ qkv,
                                                   bf16* __restrict__ o) {
  __shared__ bf16 QP[64][72];    // Q tile, then P tile (aliased; rows wv*16.. wave-private)
  __shared__ bf16 Ks[64][72];
  __shared__ bf16 Vt[64][72];    // [d][k ^ swz(d)]
  const int tid = threadIdx.x;
  const int ln = tid & 63, wv = tid >> 6;
  const int mrow = ln & 15, quad = ln >> 4;
  const int id = blockIdx.x;
  const int xcd = id & 7, j = id >> 3;
  const int qt = j & 15;
  const int pr = xcd + 8 * (j >> 4);     // 0..63
  const int hh = pr & 7, b = pr >> 3;
  const int q0 = qt * 64;
  const int sr = tid >> 2;
  const int sg = tid & 3;
  const int sc = sg * 8;

  {
    const bf16* src = qkv + (size_t)(b * S_ + q0 + sr) * D3_ + hh * 64;
    *(short8*)&QP[sr][sc]      = *(const short8*)(src + sc);
    *(short8*)&QP[sr][sc + 32] = *(const short8*)(src + sc + 32);
  }
  __syncthreads();
  short8 aq[2];
  aq[0] = *(const short8*)&QP[wv * 16 + mrow][quad * 8];
  aq[1] = *(const short8*)&QP[wv * 16 + mrow][quad * 8 + 32];

  float m_st = -1e30f, l_st = 0.f;     // state for q = mrow (replicated across quad group)
  f32x4 oacc[4];
#pragma unroll
  for (int t = 0; t < 4; t++) oacc[t] = (f32x4){0.f, 0.f, 0.f, 0.f};

  for (int kt = 0; kt < 16; kt++) {
    int k0 = kt * 64;
    __syncthreads();
    {
      const bf16* src = qkv + (size_t)(b * S_ + k0 + sr) * D3_ + D_ + hh * 64;
      *(short8*)&Ks[sr][sc]      = *(const short8*)(src + sc);
      *(short8*)&Ks[sr][sc + 32] = *(const short8*)(src + sc + 32);
    }
    {
      const bf16* src = qkv + (size_t)(b * S_ + k0 + sr) * D3_ + 2 * D_ + hh * 64;
      short8 v0 = *(const short8*)(src + sc);
      short8 v1 = *(const short8*)(src + sc + 32);
      int col0 = sr ^ (sg << 4);
      int col1 = sr ^ (((sg + 4) & 3) << 4);
#pragma unroll
      for (int u = 0; u < 8; u++) {
        *(short*)&Vt[sc + u][col0]      = v0[u];
        *(short*)&Vt[sc + 32 + u][col1] = v1[u];
      }
    }
    __syncthreads();
    // swapped QK^T: sT[t] row = k_local (quad*4+r), col = q (mrow)
    f32x4 s[4];
#pragma unroll
    for (int t = 0; t < 4; t++) {
      s[t] = (f32x4){0.f, 0.f, 0.f, 0.f};
#pragma unroll
      for (int ks = 0; ks < 2; ks++) {
        short8 bk = *(const short8*)&Ks[t * 16 + mrow][quad * 8 + ks * 32];
        s[t] = __builtin_amdgcn_mfma_f32_16x16x32_bf16(bk, aq[ks], s[t], 0, 0, 0);
      }
    }
    // in-register row stats for q = mrow over this lane's 16 k-values
    float rm = s[0][0];
#pragma unroll
    for (int t = 0; t < 4; t++)
#pragma unroll
      for (int r = 0; r < 4; r++) rm = fmaxf(rm, s[t][r]);
    rm *= 0.125f;
    rm = fmaxf(rm, __shfl_xor(rm, 16, 64));
    rm = fmaxf(rm, __shfl_xor(rm, 32, 64));
    float mnew = fmaxf(m_st, rm);
    float alpha = __expf(m_st - mnew);
    m_st = mnew;
    float rs = 0.f;
#pragma unroll
    for (int t = 0; t < 4; t++) {
      s4v pk;
#pragma unroll
      for (int r = 0; r < 4; r++) {
        float p = __expf(s[t][r] * 0.125f - mnew);
        rs += p;
        bf16 tb = __float2bfloat16(p);
        pk[r] = *(short*)&tb;
      }
      *(s4v*)&QP[wv * 16 + mrow][t * 16 + quad * 4] = pk;  // 4 contiguous k
    }
    rs += __shfl_xor(rs, 16, 64);
    rs += __shfl_xor(rs, 32, 64);
    l_st = l_st * alpha + rs;
    // rescale oacc rows (row q_local = quad*4+r; alpha lives at lane q_local)
    float af4[4];
#pragma unroll
    for (int r = 0; r < 4; r++) af4[r] = __shfl(alpha, quad * 4 + r, 64);
#pragma unroll
    for (int t = 0; t < 4; t++)
#pragma unroll
      for (int r = 0; r < 4; r++) oacc[t][r] *= af4[r];
    // PV
    short8 ap[2];
    ap[0] = *(const short8*)&QP[wv * 16 + mrow][quad * 8];
    ap[1] = *(const short8*)&QP[wv * 16 + mrow][quad * 8 + 32];
#pragma unroll
    for (int t = 0; t < 4; t++) {
      int d = t * 16 + mrow;
      int swz = ((d >> 3) & 3) << 4;
#pragma unroll
      for (int ks = 0; ks < 2; ks++) {
        short8 bv = *(const short8*)&Vt[d][(quad * 8 + ks * 32) ^ swz];
        oacc[t] = __builtin_amdgcn_mfma_f32_16x16x32_bf16(ap[ks], bv, oacc[t], 0, 0, 0);
      }
    }
  }
  float linv[4];
#pragma unroll
  for (int r = 0; r < 4; r++) linv[r] = 1.f / __shfl(l_st, quad * 4 + r, 64);
#pragma unroll
  for (int r = 0; r < 4; r++) {
    size_t base = (size_t)(b * S_ + q0 + wv * 16 + quad * 4 + r) * D_ + hh * 64;
#pragma unroll
    for (int t = 0; t < 4; t++)
      o[base + t * 16 + mrow] = __float2bfloat16(oacc[t][r] * linv[r]);
  }
}

// ---------------- fused: sum partial slices + bias + residual + LayerNorm ----------
__global__ __launch_bounds__(256) void reduce_ln_kernel(float* __restrict__ h,
                                                        bf16* __restrict__ hb16,
                                                        const bf16* __restrict__ ps,
                                                        int nsl, int mode,
                                                        const void* __restrict__ bias,
                                                        size_t boff,
                                                        const float* __restrict__ cw,
                                                        const void* __restrict__ eb2p,
                                                        size_t e2off,
                                                        const void* __restrict__ g,
                                                        const void* __restrict__ beta,
                                                        size_t off,
                                                        const int* __restrict__ flag) {
  const int bf = flag[0];
  int t = blockIdx.x, tid = threadIdx.x;
  __shared__ float r1[256], r2[256];
  const size_t base = (size_t)t * D_;
  float o0 = 0.f, o1 = 0.f;
  for (int s = 0; s < nsl; s++) {
    o0 += b2f(ps[(size_t)s * T_ * D_ + base + tid]);
    o1 += b2f(ps[(size_t)s * T_ * D_ + base + tid + 256]);
  }
  if (mode == 0) {
    o0 += ldin(bias, boff + tid, bf);
    o1 += ldin(bias, boff + tid + 256, bf);
  } else {
#pragma unroll
    for (int e = 0; e < 4; e++) {
      float w = cw[t * 4 + e];
      o0 += w * ldin(eb2p, e2off + e * D_ + tid, bf);
      o1 += w * ldin(eb2p, e2off + e * D_ + tid + 256, bf);
    }
  }
  float* hr = h + base;
  float v0 = hr[tid] + o0;
  float v1 = hr[tid + 256] + o1;
  r1[tid] = v0 + v1;
  r2[tid] = v0 * v0 + v1 * v1;
  __syncthreads();
  for (int w = 128; w; w >>= 1) { if (tid < w) { r1[tid] += r1[tid + w]; r2[tid] += r2[tid + w]; } __syncthreads(); }
  float mean = r1[0] * (1.f / D_);
  float var  = r2[0] * (1.f / D_) - mean * mean;
  float rstd = rsqrtf(var + 1e-5f);
  float n0 = (v0 - mean) * rstd * ldin(g, off + tid, bf) + ldin(beta, off + tid, bf);
  float n1 = (v1 - mean) * rstd * ldin(g, off + tid + 256, bf) + ldin(beta, off + tid + 256, bf);
  hr[tid] = n0;
  hr[tid + 256] = n1;
  hb16[base + tid] = __float2bfloat16(n0);
  hb16[base + tid + 256] = __float2bfloat16(n1);
}

// ---------------- MoE gating: softmax over E=4, top-2; emits routing info ----------
__global__ __launch_bounds__(256) void gate_kernel(const float* __restrict__ hbuf,
                                                   const void* __restrict__ gw, size_t gwoff,
                                                   const void* __restrict__ gb, size_t gboff,
                                                   float* __restrict__ cw,
                                                   int* __restrict__ einfo,
                                                   float* __restrict__ w0a,
                                                   float* __restrict__ w1a,
                                                   const int* __restrict__ flag) {
  const int bf = flag[0];
  int lane = threadIdx.x & 63, wv = threadIdx.x >> 6;
  int t = blockIdx.x * 4 + wv;
  const float* xr = hbuf + (size_t)t * D_;
  float a[4] = {0, 0, 0, 0};
  for (int d = lane; d < D_; d += 64) {
    float xv = xr[d];
#pragma unroll
    for (int e = 0; e < 4; e++) a[e] += xv * ldin(gw, gwoff + e * D_ + d, bf);
  }
#pragma unroll
  for (int e = 0; e < 4; e++)
    for (int off = 32; off; off >>= 1) a[e] += __shfl_xor(a[e], off, 64);
  if (lane == 0) {
    float lg[4];
#pragma unroll
    for (int e = 0; e < 4; e++) lg[e] = a[e] + ldin(gb, gboff + e, bf);
    float m = fmaxf(fmaxf(lg[0], lg[1]), fmaxf(lg[2], lg[3]));
    float p[4], s = 0.f;
#pragma unroll
    for (int e = 0; e < 4; e++) { p[e] = __expf(lg[e] - m); s += p[e]; }
#pragma unroll
    for (int e = 0; e < 4; e++) p[e] /= s;
    int i0 = 0;
    for (int e = 1; e < 4; e++) if (p[e] > p[i0]) i0 = e;
    int i1 = -1;
    for (int e = 0; e < 4; e++) if (e != i0 && (i1 < 0 || p[e] > p[i1])) i1 = e;
    float s2 = p[i0] + p[i1];
    float ww0 = p[i0] / s2, ww1 = p[i1] / s2;
    float outw[4] = {0, 0, 0, 0};
    outw[i0] = ww0; outw[i1] = ww1;
#pragma unroll
    for (int e = 0; e < 4; e++) cw[t * 4 + e] = outw[e];
    einfo[t] = i0 | (i1 << 4);
    w0a[t] = ww0; w1a[t] = ww1;
  }
}

// ---------------- route scan: counts -> offsets + tile table (1 block) ----------------
__global__ __launch_bounds__(256) void route_scan_kernel(const int* __restrict__ einfo,
                                                         int* __restrict__ off,
                                                         int* __restrict__ endp,
                                                         int* __restrict__ cur,
                                                         int* __restrict__ tmap) {
  __shared__ int red[4][256];
  int tid = threadIdx.x;
  int c[4] = {0, 0, 0, 0};
  for (int t = tid; t < T_; t += 256) {
    int inf = einfo[t];
    c[inf & 15]++;
    c[(inf >> 4) & 15]++;
  }
#pragma unroll
  for (int e = 0; e < 4; e++) red[e][tid] = c[e];
  __syncthreads();
  for (int w = 128; w; w >>= 1) {
    if (tid < w)
#pragma unroll
      for (int e = 0; e < 4; e++) red[e][tid] += red[e][tid + w];
    __syncthreads();
  }
  if (tid == 0) {
    int o = 0, idx = 0;
#pragma unroll
    for (int e = 0; e < 4; e++) {
      int cnt = red[e][0];
      off[e] = o;
      endp[e] = o + cnt;
      cur[e] = 0;
      int nt = (cnt + 127) >> 7;
      for (int i = 0; i < nt; i++) tmap[1 + idx++] = e | (i << 8);
      o += nt << 7;
    }
    tmap[0] = idx;   // total active m-tiles (<= 131)
  }
}

// ---------------- scatter: token -> (expert bucket, rank), ballot-aggregated --------
__global__ __launch_bounds__(256) void scatter_kernel(const int* __restrict__ einfo,
                                                      const float* __restrict__ w0a,
                                                      const float* __restrict__ w1a,
                                                      const int* __restrict__ off,
                                                      int* __restrict__ cur,
                                                      int* __restrict__ pack,
                                                      float* __restrict__ wlist) {
  int t = blockIdx.x * 256 + threadIdx.x;
  int lane = threadIdx.x & 63;
  int inf = einfo[t];
#pragma unroll
  for (int rank = 0; rank < 2; rank++) {
    int my_e = (rank == 0) ? (inf & 15) : ((inf >> 4) & 15);
    float w = (rank == 0) ? w0a[t] : w1a[t];
#pragma unroll
    for (int e = 0; e < 4; e++) {
      bool p = (my_e == e);
      unsigned long long mask = __ballot(p);
      if (!mask) continue;
      int leader = __ffsll((long long)mask) - 1;
      int base = 0;
      if (lane == leader) base = atomicAdd(&cur[e], (int)__popcll(mask));
      base = __shfl(base, leader, 64);
      if (p) {
        int pos = off[e] + base + (int)__popcll(mask & ((1ULL << lane) - 1ULL));
        pack[pos] = t * 2 + rank;
        wlist[pos] = w;
      }
    }
  }
}

// ---------------- sparse MoE mat1 (BK=32, dbuf, tile-table, XCD-swizzled) ------------
__global__ __launch_bounds__(256) void moe_mat1_kernel(
    const bf16* __restrict__ A, const bf16* __restrict__ Wt,
    const void* __restrict__ bias, size_t boff, bf16* __restrict__ hid,
    const int* __restrict__ off, const int* __restrict__ endp,
    const int* __restrict__ pack, const float* __restrict__ wlist,
    const int* __restrict__ tmap, const int* __restrict__ flag) {
  const int wbf = flag[0];
  int id = blockIdx.x + 8 * blockIdx.y;
  int xcd = id & 7, idq = id >> 3;
  int wx = idq & 7, wy = xcd + 8 * (idq >> 3);
  if (wy >= tmap[0]) return;
  int ent = tmap[1 + wy];
  const int e = ent & 255, mt = ent >> 8;
  const int o = off[e], en = endp[e];
  const int n0 = wx * 128;
  __shared__ bf16 As[2][128][32];
  __shared__ bf16 Bs[2][128][32];
  const int tid = threadIdx.x;
  const int ln = tid & 63, wv = tid >> 6;
  const int m0 = o + mt * 128;
  const int wr = (wv >> 1) * 64, wc = (wv & 1) * 64;
  const int mrow = ln & 15, quad = ln >> 4;
  const int srow = ln >> 2;
  const int skof = (ln & 3) * 8;
  int tokr[2];
#pragma unroll
  for (int j = 0; j < 2; j++) {
    int pos = m0 + 16 * (4 * j + wv) + srow;
    tokr[j] = pack[min(pos, en - 1)] >> 1;
  }
  const size_t wbase = (size_t)e * 1024 * 512;

  auto stage = [&](int pb, int k0) {
#pragma unroll
    for (int j = 0; j < 2; j++)
      gload16(A + (size_t)tokr[j] * 512 + k0 + skof,
              (char*)&As[pb][0][0] + (size_t)(4 * j + wv) * 1024);
#pragma unroll
    for (int j = 0; j < 2; j++) {
      int row = 16 * (4 * j + wv) + srow;
      gload16(Wt + wbase + (size_t)(n0 + row) * 512 + k0 + skof,
              (char*)&Bs[pb][0][0] + (size_t)(4 * j + wv) * 1024);
    }
  };

  f32x4 acc[4][4];
#pragma unroll
  for (int i = 0; i < 4; i++)
#pragma unroll
    for (int j = 0; j < 4; j++) acc[i][j] = (f32x4){0.f, 0.f, 0.f, 0.f};

  stage(0, 0);
  int p = 0;
  for (int k0 = 0; k0 < 512; k0 += 32) {
    __syncthreads();
    if (k0 + 32 < 512) stage(p ^ 1, k0 + 32);
    short8 af[4], bfr[4];
#pragma unroll
    for (int t = 0; t < 4; t++) {
      af[t]  = *(const short8*)&As[p][wr + t * 16 + mrow][quad * 8];
      bfr[t] = *(const short8*)&Bs[p][wc + t * 16 + mrow][quad * 8];
    }
#pragma unroll
    for (int i = 0; i < 4; i++)
#pragma unroll
      for (int j = 0; j < 4; j++)
        acc[i][j] = __builtin_amdgcn_mfma_f32_16x16x32_bf16(af[i], bfr[j], acc[i][j], 0, 0, 0);
    p ^= 1;
  }

#pragma unroll
  for (int ti = 0; ti < 4; ti++) {
#pragma unroll
    for (int r = 0; r < 4; r++) {
      int pos = m0 + wr + ti * 16 + quad * 4 + r;
      float w = (pos < en) ? wlist[pos] : 0.f;
#pragma unroll
      for (int tj = 0; tj < 4; tj++) {
        int ncol = n0 + wc + tj * 16 + mrow;
        float v = acc[ti][tj][r] + ldin(bias, boff + e * 1024 + ncol, wbf);
        hid[(size_t)pos * 1024 + ncol] = __float2bfloat16(fmaxf(v, 0.f) * w);
      }
    }
  }
}

// ---------------- sparse MoE mat2 (BK=32, dbuf, tile-table, XCD-swizzled, z=2) -------
__global__ __launch_bounds__(256) void moe_mat2_kernel(
    const bf16* __restrict__ hid, const bf16* __restrict__ Wt,
    bf16* __restrict__ psl,
    const int* __restrict__ off, const int* __restrict__ endp,
    const int* __restrict__ pack, const int* __restrict__ tmap,
    const int* __restrict__ flag) {
  int id = blockIdx.x + 4 * blockIdx.y;
  int xcd = id & 7, idq = id >> 3;
  int wx = idq & 3, wy = xcd + 8 * (idq >> 2);
  if (wy >= tmap[0]) return;
  int ent = tmap[1 + wy];
  const int e = ent & 255, mt = ent >> 8;
  const int o = off[e], en = endp[e];
  const int n0 = wx * 128;
  __shared__ bf16 As[2][128][32];
  __shared__ bf16 Bs[2][128][32];
  const int tid = threadIdx.x;
  const int ln = tid & 63, wv = tid >> 6;
  const int m0 = o + mt * 128;
  const int wr = (wv >> 1) * 64, wc = (wv & 1) * 64;
  const int mrow = ln & 15, quad = ln >> 4;
  const int srow = ln >> 2;
  const int skof = (ln & 3) * 8;
  const int kbeg = blockIdx.z * 512;
  const size_t wbase = (size_t)e * 512 * 1024;

  auto stage = [&](int pb, int k0) {
#pragma unroll
    for (int j = 0; j < 2; j++) {
      int row = 16 * (4 * j + wv) + srow;
      gload16(hid + (size_t)(m0 + row) * 1024 + k0 + skof,
              (char*)&As[pb][0][0] + (size_t)(4 * j + wv) * 1024);
    }
#pragma unroll
    for (int j = 0; j < 2; j++) {
      int row = 16 * (4 * j + wv) + srow;
      gload16(Wt + wbase + (size_t)(n0 + row) * 1024 + k0 + skof,
              (char*)&Bs[pb][0][0] + (size_t)(4 * j + wv) * 1024);
    }
  };

  f32x4 acc[4][4];
#pragma unroll
  for (int i = 0; i < 4; i++)
#pragma unroll
    for (int j = 0; j < 4; j++) acc[i][j] = (f32x4){0.f, 0.f, 0.f, 0.f};

  stage(0, kbeg);
  int p = 0;
  for (int k0 = kbeg; k0 < kbeg + 512; k0 += 32) {
    __syncthreads();
    if (k0 + 32 < kbeg + 512) stage(p ^ 1, k0 + 32);
    short8 af[4], bfr[4];
#pragma unroll
    for (int t = 0; t < 4; t++) {
      af[t]  = *(const short8*)&As[p][wr + t * 16 + mrow][quad * 8];
      bfr[t] = *(const short8*)&Bs[p][wc + t * 16 + mrow][quad * 8];
    }
#pragma unroll
    for (int i = 0; i < 4; i++)
#pragma unroll
      for (int j = 0; j < 4; j++)
        acc[i][j] = __builtin_amdgcn_mfma_f32_16x16x32_bf16(af[i], bfr[j], acc[i][j], 0, 0, 0);
    p ^= 1;
  }

#pragma unroll
  for (int ti = 0; ti < 4; ti++) {
#pragma unroll
    for (int r = 0; r < 4; r++) {
      int pos = m0 + wr + ti * 16 + quad * 4 + r;
      if (pos < en) {
        int pk = pack[pos];
        int tok = pk >> 1, rank = pk & 1;
        bf16* dst = psl + (size_t)(rank * 2 + blockIdx.z) * T_ * D_ + (size_t)tok * D_;
#pragma unroll
        for (int tj = 0; tj < 4; tj++) {
          int ncol = n0 + wc + tj * 16 + mrow;
          dst[ncol] = __float2bfloat16(acc[ti][tj][r]);
        }
      }
    }
  }
}

// ---------------- head ----------------
__global__ __launch_bounds__(256) void head_kernel(const float* __restrict__ hbuf,
                                                   const void* __restrict__ hw,
                                                   const void* __restrict__ hb,
                                                   void* __restrict__ out,
                                                   const int* __restrict__ flag) {
  const int bf = flag[0];
  int bq = blockIdx.x, tid = threadIdx.x;
  int b = bq / 3, q = bq % 3;
  __shared__ float red[256];
  const float* xr = hbuf + (size_t)(b * S_ + (S_ - 1)) * D_;
  float sacc = xr[tid] * ldin(hw, (size_t)q * D_ + tid, bf)
             + xr[tid + 256] * ldin(hw, (size_t)q * D_ + tid + 256, bf);
  red[tid] = sacc; __syncthreads();
  for (int w = 128; w; w >>= 1) { if (tid < w) red[tid] += red[tid + w]; __syncthreads(); }
  if (tid == 0) {
    float r = red[0] + ldin(hb, q, bf);
    if (bf) ((bf16*)out)[bq] = __float2bfloat16(r);
    else    ((float*)out)[bq] = r;
  }
}

extern "C" void kernel_launch(void* const* d_in, const int* in_sizes, int n_in,
                              void* d_out, int out_size, void* d_ws, size_t ws_size,
                              hipStream_t stream) {
  const void* x    = d_in[0];
  const void* Wp   = d_in[1];
  const void* bp   = d_in[2];
  const void* femb = d_in[3];
  const void* qkvw = d_in[4];
  const void* qkvb = d_in[5];
  const void* ow   = d_in[6];
  const void* ob   = d_in[7];
  const void* g1   = d_in[8];
  const void* be1  = d_in[9];
  const void* gw   = d_in[10];
  const void* gb   = d_in[11];
  const void* ew1  = d_in[12];
  const void* eb1  = d_in[13];
  const void* ew2  = d_in[14];
  const void* eb2  = d_in[15];
  const void* g2   = d_in[16];
  const void* be2  = d_in[17];
  const void* hw   = d_in[18];
  const void* hb   = d_in[19];
  const int*  freq = (const int*)d_in[20];

  // workspace layout: peak ~99.6 MB (within previously proven-safe 101 MB)
  int*   flag  = (int*)d_ws;                        // 64 ints
  int*   off   = flag + 64;                         // 4
  int*   endp  = off + 4;                           // 4
  int*   cur   = endp + 4;                          // 4 (+pad)
  int*   einfo = flag + 128;                        // T ints
  float* w0a   = (float*)(einfo + T_);              // T
  float* w1a   = w0a + T_;                          // T
  int*   pack  = (int*)(w1a + T_);                  // CAP ints
  float* wlist = (float*)(pack + CAP_);             // CAP
  int*   tmap  = (int*)(wlist + CAP_);              // 160 ints (count + tiles)
  float* xn    = (float*)(tmap + 160);              // 65536
  float* h     = xn + 65536;                        // T*D f    (16 MB)
  float* cw    = h + (size_t)T_ * D_;               // T*4
  bf16*  hb16  = (bf16*)(cw + (size_t)T_ * E_);     // T*D bf16 (8 MB)
  bf16*  R     = hb16 + (size_t)T_ * D_;            // alias region
  bf16*  qkvb16 = R;                                // T*3D bf16 (24 MB)
  bf16*  ao    = R + (size_t)T_ * D3_;              // T*D bf16  (8 MB)
  bf16*  hid   = R;                                 // CAP*1024 bf16 (~33 MB)
  bf16*  psl   = R + (size_t)CAP_ * 1024;           // 4x T*D bf16 (32 MB partial slices)
  bf16*  wcvt  = psl + (size_t)4 * T_ * D_;         // 8.4 MB bf16 weight scratch
  // wcvt layout phase 1 (qkv/o-proj): wq [786432], wo [262144]
  // wcvt layout phase 2 (MoE):        we1 [2097152], we2 [2097152]
  bf16*  wq    = wcvt;
  bf16*  wo    = wcvt + (size_t)D3_ * D_;
  bf16*  we1   = wcvt;
  bf16*  we2   = wcvt + (size_t)E_ * 1024 * 512;
  float* addtab = (float*)R;                        // [S][D] f32 PE table (dead before QKV GEMM)

  constexpr size_t NQ = (size_t)D3_ * D_;           // 786432
  constexpr size_t NO = (size_t)D_ * D_;            // 262144
  constexpr size_t NE = (size_t)E_ * 1024 * 512;    // 2097152

  detect_kernel<<<1, 64, 0, stream>>>(x, flag);
  instnorm_kernel<<<B_ * F_, 256, 0, stream>>>(x, xn, flag);
  pe_kernel<<<(S_ * D_ / 2) / 256, 256, 0, stream>>>(bp, femb, freq, addtab, flag);
  input_proj_kernel<<<(T_ * D_) / 256, 256, 0, stream>>>(xn, Wp, addtab, h, hb16, flag);

  for (int l = 0; l < 3; l++) {
    // convert this layer's qkv_w + ow to bf16 scratch (copy if already bf16)
    convw_kernel<<<(NQ + NO) / 2048, 256, 0, stream>>>(
        qkvw, (size_t)l * NQ, NQ, ow, (size_t)l * NO, wcvt, flag);
    // QKV projection -> bf16
    mfma_gemm<3><<<dim3(D3_ / 128, T_ / 128), 256, 0, stream>>>(
        hb16, wq, qkvb, (size_t)l * D3_, qkvb16, D_, D_, D_, D3_, flag);
    attn_kernel<<<B_ * H_ * (S_ / 64), 256, 0, stream>>>(qkvb16, ao);
    // O-projection: split-K=2 -> slices 0,1; fused reduce + bias + LN
    mfma_gemm<0><<<dim3(D_ / 128, T_ / 128, 2), 256, 0, stream>>>(
        ao, wo, nullptr, 0, psl, D_, D_, D_, D_, flag);
    reduce_ln_kernel<<<T_, 256, 0, stream>>>(
        h, hb16, psl, 2, 0, ob, (size_t)l * D_, nullptr, nullptr, 0,
        g1, be1, (size_t)l * D_, flag);
    // gating + routing
    gate_kernel<<<T_ / 4, 256, 0, stream>>>(h, gw, (size_t)l * E_ * D_, gb, (size_t)l * E_,
                                            cw, einfo, w0a, w1a, flag);
    route_scan_kernel<<<1, 256, 0, stream>>>(einfo, off, endp, cur, tmap);
    scatter_kernel<<<T_ / 256, 256, 0, stream>>>(einfo, w0a, w1a, off, cur, pack, wlist);
    // convert this layer's ew1 + ew2 to bf16 scratch (wq/wo dead past here)
    convw_kernel<<<(NE + NE) / 2048, 256, 0, stream>>>(
        ew1, (size_t)l * NE, NE, ew2, (size_t)l * NE, wcvt, flag);
    // sparse expert GEMMs (hid aliases qkv+ao, both dead here)
    moe_mat1_kernel<<<dim3(8, 136), 256, 0, stream>>>(
        hb16, we1, eb1, (size_t)l * E_ * 1024, hid,
        off, endp, pack, wlist, tmap, flag);
    moe_mat2_kernel<<<dim3(4, 136, 2), 256, 0, stream>>>(
        hid, we2, psl, off, endp, pack, tmap, flag);
    reduce_ln_kernel<<<T_, 256, 0, stream>>>(
        h, hb16, psl, 4, 1, nullptr, 0, cw, eb2, (size_t)l * E_ * D_,
        g2, be2, (size_t)l * D_, flag);
  }

  head_kernel<<<24, 256, 0, stream>>>(h, hw, hb, d_out, flag);
}

// Round 6
// 886.518 us; speedup vs baseline: 1.1384x; 1.0568x over previous
//
#include <hip/hip_runtime.h>
#include <hip/hip_bf16.h>
#include <math.h>

typedef __hip_bfloat16 bf16;
typedef __attribute__((ext_vector_type(8))) short short8;   // 8 bf16 (4 VGPRs)
typedef __attribute__((ext_vector_type(4))) short s4v;      // 4 bf16 (8 bytes)
typedef __attribute__((ext_vector_type(4))) float f32x4;

constexpr int B_ = 8, S_ = 1024, F_ = 8, D_ = 512, H_ = 8, E_ = 4;
constexpr int T_  = B_ * S_;       // 8192 tokens
constexpr int D3_ = 3 * D_;        // 1536
constexpr int CAP_ = T_ * 2 + E_ * 128;   // sparse row capacity (top-2, 128-pad/expert)

__device__ __forceinline__ float b2f(bf16 v) { return __bfloat162float(v); }
__device__ __forceinline__ float ldin(const void* p, size_t i, int bf) {
  return bf ? __bfloat162float(((const bf16*)p)[i]) : ((const float*)p)[i];
}
__device__ __forceinline__ void gload16(const void* g, void* l) {
  __builtin_amdgcn_global_load_lds((const __attribute__((address_space(1))) unsigned int*)g,
                                   (__attribute__((address_space(3))) unsigned int*)l, 16, 0, 0);
}

// ---------------- dtype detector ----------------
__global__ void detect_kernel(const void* __restrict__ x, int* __restrict__ flag) {
  if (threadIdx.x == 0 && blockIdx.x == 0) {
    const unsigned short* u = (const unsigned short*)x;
    int c = 0;
    for (int i = 0; i < 256; i += 2) {
      int ex = (u[i] >> 7) & 0xFF;
      if (ex >= 96 && ex <= 144) c++;
    }
    flag[0] = (c >= 64) ? 1 : 0;
  }
}

// ---------------- weight pre-convert: fp32 (or bf16 copy) -> bf16 scratch ----------
// Concatenates two source regions [A: nA elems][B: rest]. 8 elems/thread, vectorized.
__global__ __launch_bounds__(256) void convw_kernel(const void* __restrict__ Asrc, size_t offA,
                                                    size_t nA,
                                                    const void* __restrict__ Bsrc, size_t offB,
                                                    bf16* __restrict__ dst,
                                                    const int* __restrict__ flag) {
  const int bf = flag[0];
  size_t i = ((size_t)blockIdx.x * 256 + threadIdx.x) * 8;
  const void* s = Asrc;
  size_t so = offA + i;
  if (i >= nA) { s = Bsrc; so = offB + (i - nA); }
  if (bf) {
    *(short8*)(dst + i) = *(const short8*)((const bf16*)s + so);
  } else {
    const float* sp = (const float*)s + so;
    short8 v;
#pragma unroll
    for (int u = 0; u < 8; u++) { bf16 t = __float2bfloat16(sp[u]); v[u] = *(short*)&t; }
    *(short8*)(dst + i) = v;
  }
}

// ---------------- instance norm over time axis ----------------
__global__ __launch_bounds__(256) void instnorm_kernel(const void* __restrict__ x,
                                                       float* __restrict__ xn,
                                                       const int* __restrict__ flag) {
  const int bf = flag[0];
  int b = blockIdx.x / F_, f = blockIdx.x % F_;
  int tid = threadIdx.x;
  __shared__ float red[256];
  const int base = b * S_ * F_ + f;
  float s = 0.f;
  for (int j = tid; j < S_; j += 256) s += ldin(x, base + j * F_, bf);
  red[tid] = s; __syncthreads();
  for (int w = 128; w; w >>= 1) { if (tid < w) red[tid] += red[tid + w]; __syncthreads(); }
  float mean = red[0] / S_;
  __syncthreads();
  float v = 0.f;
  for (int j = tid; j < S_; j += 256) { float d = ldin(x, base + j * F_, bf) - mean; v += d * d; }
  red[tid] = v; __syncthreads();
  for (int w = 128; w; w >>= 1) { if (tid < w) red[tid] += red[tid + w]; __syncthreads(); }
  float inv = 1.f / (sqrtf(red[0] / (float)(S_ - 1)) + 1e-5f);
  for (int j = tid; j < S_; j += 256) xn[base + j * F_] = (ldin(x, base + j * F_, bf) - mean) * inv;
}

// ---------------- positional-encoding + bias + freq-emb add-table [S][D] -----------
// One thread per (s, even/odd d pair): one expf + one sincosf, no lane divergence.
__global__ __launch_bounds__(256) void pe_kernel(const void* __restrict__ bp,
                                                 const void* __restrict__ femb,
                                                 const int* __restrict__ freq_idx,
                                                 float* __restrict__ addtab,
                                                 const int* __restrict__ flag) {
  const int bf = flag[0];
  int idx = blockIdx.x * 256 + threadIdx.x;      // S*D/2 threads
  int dp = idx & (D_ / 2 - 1);
  int s  = idx / (D_ / 2);
  int d0 = dp * 2;
  int fi = freq_idx[0];
  const float cexp = -9.2103403719761836f / (float)D_;
  float ang = (float)s * expf((float)d0 * cexp);
  float sv, cv;
  sincosf(ang, &sv, &cv);
  addtab[(size_t)s * D_ + d0]     = sv + ldin(bp, d0, bf)     + ldin(femb, (size_t)fi * D_ + d0, bf);
  addtab[(size_t)s * D_ + d0 + 1] = cv + ldin(bp, d0 + 1, bf) + ldin(femb, (size_t)fi * D_ + d0 + 1, bf);
}

// ---------------- input projection: xn @ Wp^T + addtab -----------------------------
// Thread owns 2 consecutive d for 8 tokens: Wp rows register-cached (loaded once per
// 8 tokens, not per token), addtab/h/hb16 accessed as dense float2/uint. Kills the
// per-token 32B-stride Wp gather that made v2 L1-transaction-bound (66us @ 5% VALU).
// FMA order per d unchanged (sequential f, fp32) -> bit-identical results.
constexpr int IPG_ = 8;   // tokens per block
__global__ __launch_bounds__(256) void input_proj_kernel(const float* __restrict__ xn,
                                                         const void* __restrict__ Wp,
                                                         const float* __restrict__ addtab,
                                                         float* __restrict__ h,
                                                         bf16* __restrict__ hb16,
                                                         const int* __restrict__ flag) {
  const int bf = flag[0];
  const int tid = threadIdx.x;
  const int d0 = tid * 2;
  const int tbase = blockIdx.x * IPG_;
  float wp0[8], wp1[8];
  if (bf) {
    short8 w0 = *(const short8*)((const bf16*)Wp + (size_t)d0 * F_);
    short8 w1 = *(const short8*)((const bf16*)Wp + (size_t)(d0 + 1) * F_);
#pragma unroll
    for (int f = 0; f < 8; f++) {
      unsigned short u0 = (unsigned short)w0[f], u1 = (unsigned short)w1[f];
      wp0[f] = __bfloat162float(*(bf16*)&u0);
      wp1[f] = __bfloat162float(*(bf16*)&u1);
    }
  } else {
    const float* wpf = (const float*)Wp + (size_t)d0 * F_;
    f32x4 a = *(const f32x4*)(wpf);
    f32x4 b = *(const f32x4*)(wpf + 4);
    f32x4 c = *(const f32x4*)(wpf + 8);
    f32x4 d = *(const f32x4*)(wpf + 12);
#pragma unroll
    for (int f = 0; f < 4; f++) { wp0[f] = a[f]; wp0[4 + f] = b[f]; wp1[f] = c[f]; wp1[4 + f] = d[f]; }
  }
#pragma unroll
  for (int g = 0; g < IPG_; g++) {
    int t = tbase + g;
    int s = t & (S_ - 1);
    const float* xr = xn + (size_t)t * F_;
    f32x4 x0 = *(const f32x4*)xr;
    f32x4 x1 = *(const f32x4*)(xr + 4);
    const float2 at = *(const float2*)(addtab + (size_t)s * D_ + d0);
    float a0 = at.x, a1 = at.y;
#pragma unroll
    for (int f = 0; f < 4; f++) { a0 += x0[f] * wp0[f]; a1 += x0[f] * wp1[f]; }
#pragma unroll
    for (int f = 0; f < 4; f++) { a0 += x1[f] * wp0[4 + f]; a1 += x1[f] * wp1[4 + f]; }
    *(float2*)(h + (size_t)t * D_ + d0) = make_float2(a0, a1);
    bf16 b0 = __float2bfloat16(a0), b1 = __float2bfloat16(a1);
    unsigned pk = (unsigned)(*(unsigned short*)&b0) | ((unsigned)(*(unsigned short*)&b1) << 16);
    *(unsigned*)(hb16 + (size_t)t * D_ + d0) = pk;
  }
}

// ---------------- dense MFMA GEMM, BK=32, dbuf single-barrier K-loop, XCD swizzle ----
// B operand is pre-converted bf16 (async global_load_lds both operands).
// MODE 3: C bf16 = acc + bias  (QKV). MODE 0: partial bf16 slice per z (O-proj).
// Requires gridDim.y % 8 == 0 for the swizzle.
template <int MODE>
__global__ __launch_bounds__(256) void mfma_gemm(
    const bf16* __restrict__ A, const bf16* __restrict__ Wt,
    const void* __restrict__ bias, size_t boff, void* __restrict__ C_,
    int Kd, int lda, int ldb, int ldc, const int* __restrict__ flag) {
  const int wbf = flag[0];
  __shared__ bf16 As[2][128][32];
  __shared__ bf16 Bs[2][128][32];
  const int tid = threadIdx.x;
  const int ln = tid & 63, wv = tid >> 6;
  int id = blockIdx.x + gridDim.x * blockIdx.y;
  int xcd = id & 7, idq = id >> 3;
  const int n0 = (idq % gridDim.x) * 128;
  const int m0 = (xcd + 8 * (idq / gridDim.x)) * 128;
  const int wr = (wv >> 1) * 64, wc = (wv & 1) * 64;
  const int mrow = ln & 15, quad = ln >> 4;
  const int srow = ln >> 2;
  const int skof = (ln & 3) * 8;
  const int kchunk = Kd / gridDim.z;
  const int kbeg = blockIdx.z * kchunk;
  const int kend = kbeg + kchunk;

  auto stage = [&](int pb, int k0) {
#pragma unroll
    for (int j = 0; j < 2; j++) {
      int row = 16 * (4 * j + wv) + srow;
      gload16(A + (size_t)(m0 + row) * lda + k0 + skof,
              (char*)&As[pb][0][0] + (size_t)(4 * j + wv) * 1024);
    }
#pragma unroll
    for (int j = 0; j < 2; j++) {
      int row = 16 * (4 * j + wv) + srow;
      gload16(Wt + (size_t)(n0 + row) * ldb + k0 + skof,
              (char*)&Bs[pb][0][0] + (size_t)(4 * j + wv) * 1024);
    }
  };

  f32x4 acc[4][4];
#pragma unroll
  for (int i = 0; i < 4; i++)
#pragma unroll
    for (int j = 0; j < 4; j++) acc[i][j] = (f32x4){0.f, 0.f, 0.f, 0.f};

  stage(0, kbeg);
  int p = 0;
  for (int k0 = kbeg; k0 < kend; k0 += 32) {
    __syncthreads();                       // drains prefetch into buf p (vmcnt before barrier)
    if (k0 + 32 < kend) stage(p ^ 1, k0 + 32);   // in flight during compute
    short8 af[4], bfr[4];
#pragma unroll
    for (int t = 0; t < 4; t++) {
      af[t]  = *(const short8*)&As[p][wr + t * 16 + mrow][quad * 8];
      bfr[t] = *(const short8*)&Bs[p][wc + t * 16 + mrow][quad * 8];
    }
#pragma unroll
    for (int i = 0; i < 4; i++)
#pragma unroll
      for (int j = 0; j < 4; j++)
        acc[i][j] = __builtin_amdgcn_mfma_f32_16x16x32_bf16(af[i], bfr[j], acc[i][j], 0, 0, 0);
    p ^= 1;
  }

  bf16* slice = (MODE == 0) ? (bf16*)C_ + (size_t)blockIdx.z * T_ * D_ : (bf16*)C_;
#pragma unroll
  for (int tj = 0; tj < 4; tj++) {
    int n = n0 + wc + tj * 16 + mrow;
    float bv = (MODE == 3) ? ldin(bias, boff + n, wbf) : 0.f;
#pragma unroll
    for (int ti = 0; ti < 4; ti++) {
      int mbase = m0 + wr + ti * 16 + quad * 4;
#pragma unroll
      for (int r = 0; r < 4; r++) {
        int m = mbase + r;
        float v = acc[ti][tj][r];
        slice[(size_t)m * ldc + n] = __float2bfloat16(MODE == 3 ? v + bv : v);
      }
    }
  }
}

// ---------------- MFMA flash attention: 64-query tile, swapped QK^T softmax --------
// sT = mfma(K_frag, Q_frag): lane holds the full 64-wide P row for q = lane&15
// (k = t*16 + quad*4 + r). Row max/sum = in-register reduce + 2 shfl_xor (quad group).
// P spill = 4x ds_write_b64; m/l state scalar per lane. P region is wave-private.
__global__ __launch_bounds__(256) void attn_kernel(const bf16* __restrict__ qkv,
                                                   bf16* __restrict__ o) {
  __shared__ bf16 QP[64][72];    // Q tile, then P tile (aliased; rows wv*16.. wave-private)
  __shared__ bf16 Ks[64][72];
  __shared__ bf16 Vt[64][72];    // [d][k ^ swz(d)]
  const int tid = threadIdx.x;
  const int ln = tid & 63, wv = tid >> 6;
  const int mrow = ln & 15, quad = ln >> 4;
  const int id = blockIdx.x;
  const int xcd = id & 7, j = id >> 3;
  const int qt = j & 15;
  const int pr = xcd + 8 * (j >> 4);     // 0..63
  const int hh = pr & 7, b = pr >> 3;
  const int q0 = qt * 64;
  const int sr = tid >> 2;
  const int sg = tid & 3;
  const int sc = sg * 8;

  {
    const bf16* src = qkv + (size_t)(b * S_ + q0 + sr) * D3_ + hh * 64;
    *(short8*)&QP[sr][sc]      = *(const short8*)(src + sc);
    *(short8*)&QP[sr][sc + 32] = *(const short8*)(src + sc + 32);
  }
  __syncthreads();
  short8 aq[2];
  aq[0] = *(const short8*)&QP[wv * 16 + mrow][quad * 8];
  aq[1] = *(const short8*)&QP[wv * 16 + mrow][quad * 8 + 32];

  float m_st = -1e30f, l_st = 0.f;     // state for q = mrow (replicated across quad group)
  f32x4 oacc[4];
#pragma unroll
  for (int t = 0; t < 4; t++) oacc[t] = (f32x4){0.f, 0.f, 0.f, 0.f};

  for (int kt = 0; kt < 16; kt++) {
    int k0 = kt * 64;
    __syncthreads();
    {
      const bf16* src = qkv + (size_t)(b * S_ + k0 + sr) * D3_ + D_ + hh * 64;
      *(short8*)&Ks[sr][sc]      = *(const short8*)(src + sc);
      *(short8*)&Ks[sr][sc + 32] = *(const short8*)(src + sc + 32);
    }
    {
      const bf16* src = qkv + (size_t)(b * S_ + k0 + sr) * D3_ + 2 * D_ + hh * 64;
      short8 v0 = *(const short8*)(src + sc);
      short8 v1 = *(const short8*)(src + sc + 32);
      int col0 = sr ^ (sg << 4);
      int col1 = sr ^ (((sg + 4) & 3) << 4);
#pragma unroll
      for (int u = 0; u < 8; u++) {
        *(short*)&Vt[sc + u][col0]      = v0[u];
        *(short*)&Vt[sc + 32 + u][col1] = v1[u];
      }
    }
    __syncthreads();
    // swapped QK^T: sT[t] row = k_local (quad*4+r), col = q (mrow)
    f32x4 s[4];
#pragma unroll
    for (int t = 0; t < 4; t++) {
      s[t] = (f32x4){0.f, 0.f, 0.f, 0.f};
#pragma unroll
      for (int ks = 0; ks < 2; ks++) {
        short8 bk = *(const short8*)&Ks[t * 16 + mrow][quad * 8 + ks * 32];
        s[t] = __builtin_amdgcn_mfma_f32_16x16x32_bf16(bk, aq[ks], s[t], 0, 0, 0);
      }
    }
    // in-register row stats for q = mrow over this lane's 16 k-values
    float rm = s[0][0];
#pragma unroll
    for (int t = 0; t < 4; t++)
#pragma unroll
      for (int r = 0; r < 4; r++) rm = fmaxf(rm, s[t][r]);
    rm *= 0.125f;
    rm = fmaxf(rm, __shfl_xor(rm, 16, 64));
    rm = fmaxf(rm, __shfl_xor(rm, 32, 64));
    float mnew = fmaxf(m_st, rm);
    float alpha = __expf(m_st - mnew);
    m_st = mnew;
    float rs = 0.f;
#pragma unroll
    for (int t = 0; t < 4; t++) {
      s4v pk;
#pragma unroll
      for (int r = 0; r < 4; r++) {
        float p = __expf(s[t][r] * 0.125f - mnew);
        rs += p;
        bf16 tb = __float2bfloat16(p);
        pk[r] = *(short*)&tb;
      }
      *(s4v*)&QP[wv * 16 + mrow][t * 16 + quad * 4] = pk;  // 4 contiguous k
    }
    rs += __shfl_xor(rs, 16, 64);
    rs += __shfl_xor(rs, 32, 64);
    l_st = l_st * alpha + rs;
    // rescale oacc rows (row q_local = quad*4+r; alpha lives at lane q_local)
    float af4[4];
#pragma unroll
    for (int r = 0; r < 4; r++) af4[r] = __shfl(alpha, quad * 4 + r, 64);
#pragma unroll
    for (int t = 0; t < 4; t++)
#pragma unroll
      for (int r = 0; r < 4; r++) oacc[t][r] *= af4[r];
    // PV
    short8 ap[2];
    ap[0] = *(const short8*)&QP[wv * 16 + mrow][quad * 8];
    ap[1] = *(const short8*)&QP[wv * 16 + mrow][quad * 8 + 32];
#pragma unroll
    for (int t = 0; t < 4; t++) {
      int d = t * 16 + mrow;
      int swz = ((d >> 3) & 3) << 4;
#pragma unroll
      for (int ks = 0; ks < 2; ks++) {
        short8 bv = *(const short8*)&Vt[d][(quad * 8 + ks * 32) ^ swz];
        oacc[t] = __builtin_amdgcn_mfma_f32_16x16x32_bf16(ap[ks], bv, oacc[t], 0, 0, 0);
      }
    }
  }
  float linv[4];
#pragma unroll
  for (int r = 0; r < 4; r++) linv[r] = 1.f / __shfl(l_st, quad * 4 + r, 64);
#pragma unroll
  for (int r = 0; r < 4; r++) {
    size_t base = (size_t)(b * S_ + q0 + wv * 16 + quad * 4 + r) * D_ + hh * 64;
#pragma unroll
    for (int t = 0; t < 4; t++)
      o[base + t * 16 + mrow] = __float2bfloat16(oacc[t][r] * linv[r]);
  }
}

// ---------------- fused: sum partial slices + bias + residual + LayerNorm ----------
__global__ __launch_bounds__(256) void reduce_ln_kernel(float* __restrict__ h,
                                                        bf16* __restrict__ hb16,
                                                        const bf16* __restrict__ ps,
                                                        int nsl, int mode,
                                                        const void* __restrict__ bias,
                                                        size_t boff,
                                                        const float* __restrict__ cw,
                                                        const void* __restrict__ eb2p,
                                                        size_t e2off,
                                                        const void* __restrict__ g,
                                                        const void* __restrict__ beta,
                                                        size_t off,
                                                        const int* __restrict__ flag) {
  const int bf = flag[0];
  int t = blockIdx.x, tid = threadIdx.x;
  __shared__ float r1[256], r2[256];
  const size_t base = (size_t)t * D_;
  float o0 = 0.f, o1 = 0.f;
  for (int s = 0; s < nsl; s++) {
    o0 += b2f(ps[(size_t)s * T_ * D_ + base + tid]);
    o1 += b2f(ps[(size_t)s * T_ * D_ + base + tid + 256]);
  }
  if (mode == 0) {
    o0 += ldin(bias, boff + tid, bf);
    o1 += ldin(bias, boff + tid + 256, bf);
  } else {
#pragma unroll
    for (int e = 0; e < 4; e++) {
      float w = cw[t * 4 + e];
      o0 += w * ldin(eb2p, e2off + e * D_ + tid, bf);
      o1 += w * ldin(eb2p, e2off + e * D_ + tid + 256, bf);
    }
  }
  float* hr = h + base;
  float v0 = hr[tid] + o0;
  float v1 = hr[tid + 256] + o1;
  r1[tid] = v0 + v1;
  r2[tid] = v0 * v0 + v1 * v1;
  __syncthreads();
  for (int w = 128; w; w >>= 1) { if (tid < w) { r1[tid] += r1[tid + w]; r2[tid] += r2[tid + w]; } __syncthreads(); }
  float mean = r1[0] * (1.f / D_);
  float var  = r2[0] * (1.f / D_) - mean * mean;
  float rstd = rsqrtf(var + 1e-5f);
  float n0 = (v0 - mean) * rstd * ldin(g, off + tid, bf) + ldin(beta, off + tid, bf);
  float n1 = (v1 - mean) * rstd * ldin(g, off + tid + 256, bf) + ldin(beta, off + tid + 256, bf);
  hr[tid] = n0;
  hr[tid + 256] = n1;
  hb16[base + tid] = __float2bfloat16(n0);
  hb16[base + tid + 256] = __float2bfloat16(n1);
}

// ---------------- MoE gating: softmax over E=4, top-2; emits routing info ----------
__global__ __launch_bounds__(256) void gate_kernel(const float* __restrict__ hbuf,
                                                   const void* __restrict__ gw, size_t gwoff,
                                                   const void* __restrict__ gb, size_t gboff,
                                                   float* __restrict__ cw,
                                                   int* __restrict__ einfo,
                                                   float* __restrict__ w0a,
                                                   float* __restrict__ w1a,
                                                   const int* __restrict__ flag) {
  const int bf = flag[0];
  int lane = threadIdx.x & 63, wv = threadIdx.x >> 6;
  int t = blockIdx.x * 4 + wv;
  const float* xr = hbuf + (size_t)t * D_;
  float a[4] = {0, 0, 0, 0};
  for (int d = lane; d < D_; d += 64) {
    float xv = xr[d];
#pragma unroll
    for (int e = 0; e < 4; e++) a[e] += xv * ldin(gw, gwoff + e * D_ + d, bf);
  }
#pragma unroll
  for (int e = 0; e < 4; e++)
    for (int off = 32; off; off >>= 1) a[e] += __shfl_xor(a[e], off, 64);
  if (lane == 0) {
    float lg[4];
#pragma unroll
    for (int e = 0; e < 4; e++) lg[e] = a[e] + ldin(gb, gboff + e, bf);
    float m = fmaxf(fmaxf(lg[0], lg[1]), fmaxf(lg[2], lg[3]));
    float p[4], s = 0.f;
#pragma unroll
    for (int e = 0; e < 4; e++) { p[e] = __expf(lg[e] - m); s += p[e]; }
#pragma unroll
    for (int e = 0; e < 4; e++) p[e] /= s;
    int i0 = 0;
    for (int e = 1; e < 4; e++) if (p[e] > p[i0]) i0 = e;
    int i1 = -1;
    for (int e = 0; e < 4; e++) if (e != i0 && (i1 < 0 || p[e] > p[i1])) i1 = e;
    float s2 = p[i0] + p[i1];
    float ww0 = p[i0] / s2, ww1 = p[i1] / s2;
    float outw[4] = {0, 0, 0, 0};
    outw[i0] = ww0; outw[i1] = ww1;
#pragma unroll
    for (int e = 0; e < 4; e++) cw[t * 4 + e] = outw[e];
    einfo[t] = i0 | (i1 << 4);
    w0a[t] = ww0; w1a[t] = ww1;
  }
}

// ---------------- route scan: counts -> offsets + tile table (1 block) ----------------
__global__ __launch_bounds__(256) void route_scan_kernel(const int* __restrict__ einfo,
                                                         int* __restrict__ off,
                                                         int* __restrict__ endp,
                                                         int* __restrict__ cur,
                                                         int* __restrict__ tmap) {
  __shared__ int red[4][256];
  int tid = threadIdx.x;
  int c[4] = {0, 0, 0, 0};
  for (int t = tid; t < T_; t += 256) {
    int inf = einfo[t];
    c[inf & 15]++;
    c[(inf >> 4) & 15]++;
  }
#pragma unroll
  for (int e = 0; e < 4; e++) red[e][tid] = c[e];
  __syncthreads();
  for (int w = 128; w; w >>= 1) {
    if (tid < w)
#pragma unroll
      for (int e = 0; e < 4; e++) red[e][tid] += red[e][tid + w];
    __syncthreads();
  }
  if (tid == 0) {
    int o = 0, idx = 0;
#pragma unroll
    for (int e = 0; e < 4; e++) {
      int cnt = red[e][0];
      off[e] = o;
      endp[e] = o + cnt;
      cur[e] = 0;
      int nt = (cnt + 127) >> 7;
      for (int i = 0; i < nt; i++) tmap[1 + idx++] = e | (i << 8);
      o += nt << 7;
    }
    tmap[0] = idx;   // total active m-tiles (<= 131)
  }
}

// ---------------- scatter: token -> (expert bucket, rank), ballot-aggregated --------
__global__ __launch_bounds__(256) void scatter_kernel(const int* __restrict__ einfo,
                                                      const float* __restrict__ w0a,
                                                      const float* __restrict__ w1a,
                                                      const int* __restrict__ off,
                                                      int* __restrict__ cur,
                                                      int* __restrict__ pack,
                                                      float* __restrict__ wlist) {
  int t = blockIdx.x * 256 + threadIdx.x;
  int lane = threadIdx.x & 63;
  int inf = einfo[t];
#pragma unroll
  for (int rank = 0; rank < 2; rank++) {
    int my_e = (rank == 0) ? (inf & 15) : ((inf >> 4) & 15);
    float w = (rank == 0) ? w0a[t] : w1a[t];
#pragma unroll
    for (int e = 0; e < 4; e++) {
      bool p = (my_e == e);
      unsigned long long mask = __ballot(p);
      if (!mask) continue;
      int leader = __ffsll((long long)mask) - 1;
      int base = 0;
      if (lane == leader) base = atomicAdd(&cur[e], (int)__popcll(mask));
      base = __shfl(base, leader, 64);
      if (p) {
        int pos = off[e] + base + (int)__popcll(mask & ((1ULL << lane) - 1ULL));
        pack[pos] = t * 2 + rank;
        wlist[pos] = w;
      }
    }
  }
}

// ---------------- sparse MoE mat1 (BK=32, dbuf, tile-table, XCD-swizzled) ------------
__global__ __launch_bounds__(256) void moe_mat1_kernel(
    const bf16* __restrict__ A, const bf16* __restrict__ Wt,
    const void* __restrict__ bias, size_t boff, bf16* __restrict__ hid,
    const int* __restrict__ off, const int* __restrict__ endp,
    const int* __restrict__ pack, const float* __restrict__ wlist,
    const int* __restrict__ tmap, const int* __restrict__ flag) {
  const int wbf = flag[0];
  int id = blockIdx.x + 8 * blockIdx.y;
  int xcd = id & 7, idq = id >> 3;
  int wx = idq & 7, wy = xcd + 8 * (idq >> 3);
  if (wy >= tmap[0]) return;
  int ent = tmap[1 + wy];
  const int e = ent & 255, mt = ent >> 8;
  const int o = off[e], en = endp[e];
  const int n0 = wx * 128;
  __shared__ bf16 As[2][128][32];
  __shared__ bf16 Bs[2][128][32];
  const int tid = threadIdx.x;
  const int ln = tid & 63, wv = tid >> 6;
  const int m0 = o + mt * 128;
  const int wr = (wv >> 1) * 64, wc = (wv & 1) * 64;
  const int mrow = ln & 15, quad = ln >> 4;
  const int srow = ln >> 2;
  const int skof = (ln & 3) * 8;
  int tokr[2];
#pragma unroll
  for (int j = 0; j < 2; j++) {
    int pos = m0 + 16 * (4 * j + wv) + srow;
    tokr[j] = pack[min(pos, en - 1)] >> 1;
  }
  const size_t wbase = (size_t)e * 1024 * 512;

  auto stage = [&](int pb, int k0) {
#pragma unroll
    for (int j = 0; j < 2; j++)
      gload16(A + (size_t)tokr[j] * 512 + k0 + skof,
              (char*)&As[pb][0][0] + (size_t)(4 * j + wv) * 1024);
#pragma unroll
    for (int j = 0; j < 2; j++) {
      int row = 16 * (4 * j + wv) + srow;
      gload16(Wt + wbase + (size_t)(n0 + row) * 512 + k0 + skof,
              (char*)&Bs[pb][0][0] + (size_t)(4 * j + wv) * 1024);
    }
  };

  f32x4 acc[4][4];
#pragma unroll
  for (int i = 0; i < 4; i++)
#pragma unroll
    for (int j = 0; j < 4; j++) acc[i][j] = (f32x4){0.f, 0.f, 0.f, 0.f};

  stage(0, 0);
  int p = 0;
  for (int k0 = 0; k0 < 512; k0 += 32) {
    __syncthreads();
    if (k0 + 32 < 512) stage(p ^ 1, k0 + 32);
    short8 af[4], bfr[4];
#pragma unroll
    for (int t = 0; t < 4; t++) {
      af[t]  = *(const short8*)&As[p][wr + t * 16 + mrow][quad * 8];
      bfr[t] = *(const short8*)&Bs[p][wc + t * 16 + mrow][quad * 8];
    }
#pragma unroll
    for (int i = 0; i < 4; i++)
#pragma unroll
      for (int j = 0; j < 4; j++)
        acc[i][j] = __builtin_amdgcn_mfma_f32_16x16x32_bf16(af[i], bfr[j], acc[i][j], 0, 0, 0);
    p ^= 1;
  }

#pragma unroll
  for (int ti = 0; ti < 4; ti++) {
#pragma unroll
    for (int r = 0; r < 4; r++) {
      int pos = m0 + wr + ti * 16 + quad * 4 + r;
      float w = (pos < en) ? wlist[pos] : 0.f;
#pragma unroll
      for (int tj = 0; tj < 4; tj++) {
        int ncol = n0 + wc + tj * 16 + mrow;
        float v = acc[ti][tj][r] + ldin(bias, boff + e * 1024 + ncol, wbf);
        hid[(size_t)pos * 1024 + ncol] = __float2bfloat16(fmaxf(v, 0.f) * w);
      }
    }
  }
}

// ---------------- sparse MoE mat2 (BK=32, dbuf, tile-table, XCD-swizzled, z=2) -------
__global__ __launch_bounds__(256) void moe_mat2_kernel(
    const bf16* __restrict__ hid, const bf16* __restrict__ Wt,
    bf16* __restrict__ psl,
    const int* __restrict__ off, const int* __restrict__ endp,
    const int* __restrict__ pack, const int* __restrict__ tmap,
    const int* __restrict__ flag) {
  int id = blockIdx.x + 4 * blockIdx.y;
  int xcd = id & 7, idq = id >> 3;
  int wx = idq & 3, wy = xcd + 8 * (idq >> 2);
  if (wy >= tmap[0]) return;
  int ent = tmap[1 + wy];
  const int e = ent & 255, mt = ent >> 8;
  const int o = off[e], en = endp[e];
  const int n0 = wx * 128;
  __shared__ bf16 As[2][128][32];
  __shared__ bf16 Bs[2][128][32];
  const int tid = threadIdx.x;
  const int ln = tid & 63, wv = tid >> 6;
  const int m0 = o + mt * 128;
  const int wr = (wv >> 1) * 64, wc = (wv & 1) * 64;
  const int mrow = ln & 15, quad = ln >> 4;
  const int srow = ln >> 2;
  const int skof = (ln & 3) * 8;
  const int kbeg = blockIdx.z * 512;
  const size_t wbase = (size_t)e * 512 * 1024;

  auto stage = [&](int pb, int k0) {
#pragma unroll
    for (int j = 0; j < 2; j++) {
      int row = 16 * (4 * j + wv) + srow;
      gload16(hid + (size_t)(m0 + row) * 1024 + k0 + skof,
              (char*)&As[pb][0][0] + (size_t)(4 * j + wv) * 1024);
    }
#pragma unroll
    for (int j = 0; j < 2; j++) {
      int row = 16 * (4 * j + wv) + srow;
      gload16(Wt + wbase + (size_t)(n0 + row) * 1024 + k0 + skof,
              (char*)&Bs[pb][0][0] + (size_t)(4 * j + wv) * 1024);
    }
  };

  f32x4 acc[4][4];
#pragma unroll
  for (int i = 0; i < 4; i++)
#pragma unroll
    for (int j = 0; j < 4; j++) acc[i][j] = (f32x4){0.f, 0.f, 0.f, 0.f};

  stage(0, kbeg);
  int p = 0;
  for (int k0 = kbeg; k0 < kbeg + 512; k0 += 32) {
    __syncthreads();
    if (k0 + 32 < kbeg + 512) stage(p ^ 1, k0 + 32);
    short8 af[4], bfr[4];
#pragma unroll
    for (int t = 0; t < 4; t++) {
      af[t]  = *(const short8*)&As[p][wr + t * 16 + mrow][quad * 8];
      bfr[t] = *(const short8*)&Bs[p][wc + t * 16 + mrow][quad * 8];
    }
#pragma unroll
    for (int i = 0; i < 4; i++)
#pragma unroll
      for (int j = 0; j < 4; j++)
        acc[i][j] = __builtin_amdgcn_mfma_f32_16x16x32_bf16(af[i], bfr[j], acc[i][j], 0, 0, 0);
    p ^= 1;
  }

#pragma unroll
  for (int ti = 0; ti < 4; ti++) {
#pragma unroll
    for (int r = 0; r < 4; r++) {
      int pos = m0 + wr + ti * 16 + quad * 4 + r;
      if (pos < en) {
        int pk = pack[pos];
        int tok = pk >> 1, rank = pk & 1;
        bf16* dst = psl + (size_t)(rank * 2 + blockIdx.z) * T_ * D_ + (size_t)tok * D_;
#pragma unroll
        for (int tj = 0; tj < 4; tj++) {
          int ncol = n0 + wc + tj * 16 + mrow;
          dst[ncol] = __float2bfloat16(acc[ti][tj][r]);
        }
      }
    }
  }
}

// ---------------- head ----------------
__global__ __launch_bounds__(256) void head_kernel(const float* __restrict__ hbuf,
                                                   const void* __restrict__ hw,
                                                   const void* __restrict__ hb,
                                                   void* __restrict__ out,
                                                   const int* __restrict__ flag) {
  const int bf = flag[0];
  int bq = blockIdx.x, tid = threadIdx.x;
  int b = bq / 3, q = bq % 3;
  __shared__ float red[256];
  const float* xr = hbuf + (size_t)(b * S_ + (S_ - 1)) * D_;
  float sacc = xr[tid] * ldin(hw, (size_t)q * D_ + tid, bf)
             + xr[tid + 256] * ldin(hw, (size_t)q * D_ + tid + 256, bf);
  red[tid] = sacc; __syncthreads();
  for (int w = 128; w; w >>= 1) { if (tid < w) red[tid] += red[tid + w]; __syncthreads(); }
  if (tid == 0) {
    float r = red[0] + ldin(hb, q, bf);
    if (bf) ((bf16*)out)[bq] = __float2bfloat16(r);
    else    ((float*)out)[bq] = r;
  }
}

extern "C" void kernel_launch(void* const* d_in, const int* in_sizes, int n_in,
                              void* d_out, int out_size, void* d_ws, size_t ws_size,
                              hipStream_t stream) {
  const void* x    = d_in[0];
  const void* Wp   = d_in[1];
  const void* bp   = d_in[2];
  const void* femb = d_in[3];
  const void* qkvw = d_in[4];
  const void* qkvb = d_in[5];
  const void* ow   = d_in[6];
  const void* ob   = d_in[7];
  const void* g1   = d_in[8];
  const void* be1  = d_in[9];
  const void* gw   = d_in[10];
  const void* gb   = d_in[11];
  const void* ew1  = d_in[12];
  const void* eb1  = d_in[13];
  const void* ew2  = d_in[14];
  const void* eb2  = d_in[15];
  const void* g2   = d_in[16];
  const void* be2  = d_in[17];
  const void* hw   = d_in[18];
  const void* hb   = d_in[19];
  const int*  freq = (const int*)d_in[20];

  // workspace layout: peak ~99.6 MB (within previously proven-safe 101 MB)
  int*   flag  = (int*)d_ws;                        // 64 ints
  int*   off   = flag + 64;                         // 4
  int*   endp  = off + 4;                           // 4
  int*   cur   = endp + 4;                          // 4 (+pad)
  int*   einfo = flag + 128;                        // T ints
  float* w0a   = (float*)(einfo + T_);              // T
  float* w1a   = w0a + T_;                          // T
  int*   pack  = (int*)(w1a + T_);                  // CAP ints
  float* wlist = (float*)(pack + CAP_);             // CAP
  int*   tmap  = (int*)(wlist + CAP_);              // 160 ints (count + tiles)
  float* xn    = (float*)(tmap + 160);              // 65536
  float* h     = xn + 65536;                        // T*D f    (16 MB)
  float* cw    = h + (size_t)T_ * D_;               // T*4
  bf16*  hb16  = (bf16*)(cw + (size_t)T_ * E_);     // T*D bf16 (8 MB)
  bf16*  R     = hb16 + (size_t)T_ * D_;            // alias region
  bf16*  qkvb16 = R;                                // T*3D bf16 (24 MB)
  bf16*  ao    = R + (size_t)T_ * D3_;              // T*D bf16  (8 MB)
  bf16*  hid   = R;                                 // CAP*1024 bf16 (~33 MB)
  bf16*  psl   = R + (size_t)CAP_ * 1024;           // 4x T*D bf16 (32 MB partial slices)
  bf16*  wcvt  = psl + (size_t)4 * T_ * D_;         // 8.4 MB bf16 weight scratch
  // wcvt layout phase 1 (qkv/o-proj): wq [786432], wo [262144]
  // wcvt layout phase 2 (MoE):        we1 [2097152], we2 [2097152]
  bf16*  wq    = wcvt;
  bf16*  wo    = wcvt + (size_t)D3_ * D_;
  bf16*  we1   = wcvt;
  bf16*  we2   = wcvt + (size_t)E_ * 1024 * 512;
  float* addtab = (float*)R;                        // [S][D] f32 PE table (dead before QKV GEMM)

  constexpr size_t NQ = (size_t)D3_ * D_;           // 786432
  constexpr size_t NO = (size_t)D_ * D_;            // 262144
  constexpr size_t NE = (size_t)E_ * 1024 * 512;    // 2097152

  detect_kernel<<<1, 64, 0, stream>>>(x, flag);
  instnorm_kernel<<<B_ * F_, 256, 0, stream>>>(x, xn, flag);
  pe_kernel<<<(S_ * D_ / 2) / 256, 256, 0, stream>>>(bp, femb, freq, addtab, flag);
  input_proj_kernel<<<T_ / IPG_, 256, 0, stream>>>(xn, Wp, addtab, h, hb16, flag);

  for (int l = 0; l < 3; l++) {
    // convert this layer's qkv_w + ow to bf16 scratch (copy if already bf16)
    convw_kernel<<<(NQ + NO) / 2048, 256, 0, stream>>>(
        qkvw, (size_t)l * NQ, NQ, ow, (size_t)l * NO, wcvt, flag);
    // QKV projection -> bf16
    mfma_gemm<3><<<dim3(D3_ / 128, T_ / 128), 256, 0, stream>>>(
        hb16, wq, qkvb, (size_t)l * D3_, qkvb16, D_, D_, D_, D3_, flag);
    attn_kernel<<<B_ * H_ * (S_ / 64), 256, 0, stream>>>(qkvb16, ao);
    // O-projection: split-K=2 -> slices 0,1; fused reduce + bias + LN
    mfma_gemm<0><<<dim3(D_ / 128, T_ / 128, 2), 256, 0, stream>>>(
        ao, wo, nullptr, 0, psl, D_, D_, D_, D_, flag);
    reduce_ln_kernel<<<T_, 256, 0, stream>>>(
        h, hb16, psl, 2, 0, ob, (size_t)l * D_, nullptr, nullptr, 0,
        g1, be1, (size_t)l * D_, flag);
    // gating + routing
    gate_kernel<<<T_ / 4, 256, 0, stream>>>(h, gw, (size_t)l * E_ * D_, gb, (size_t)l * E_,
                                            cw, einfo, w0a, w1a, flag);
    route_scan_kernel<<<1, 256, 0, stream>>>(einfo, off, endp, cur, tmap);
    scatter_kernel<<<T_ / 256, 256, 0, stream>>>(einfo, w0a, w1a, off, cur, pack, wlist);
    // convert this layer's ew1 + ew2 to bf16 scratch (wq/wo dead past here)
    convw_kernel<<<(NE + NE) / 2048, 256, 0, stream>>>(
        ew1, (size_t)l * NE, NE, ew2, (size_t)l * NE, wcvt, flag);
    // sparse expert GEMMs (hid aliases qkv+ao, both dead here)
    moe_mat1_kernel<<<dim3(8, 136), 256, 0, stream>>>(
        hb16, we1, eb1, (size_t)l * E_ * 1024, hid,
        off, endp, pack, wlist, tmap, flag);
    moe_mat2_kernel<<<dim3(4, 136, 2), 256, 0, stream>>>(
        hid, we2, psl, off, endp, pack, tmap, flag);
    reduce_ln_kernel<<<T_, 256, 0, stream>>>(
        h, hb16, psl, 4, 1, nullptr, 0, cw, eb2, (size_t)l * E_ * D_,
        g2, be2, (size_t)l * D_, flag);
  }

  head_kernel<<<24, 256, 0, stream>>>(h, hw, hb, d_out, flag);
}